// Round 13
// baseline (1220.179 us; speedup 1.0000x reference)
//
#include <hip/hip_runtime.h>
#include <math.h>

#define E_TOT 65536
#define B_G   128
#define QLD   1664   // fused buffer row: [S(128) | Q/O(512) | K/outT0(512) | V/outT1(512)]
#define NCOL  1728   // GEMM cols: QLD + 64 (U = We^T q projection)

typedef __attribute__((ext_vector_type(8))) short short8;
typedef __attribute__((ext_vector_type(4))) float float4v;

__device__ __forceinline__ unsigned short f2bf(float f) {
    unsigned int u = __float_as_uint(f);
    unsigned int r = u + 0x7FFFu + ((u >> 16) & 1u);   // round-to-nearest-even
    return (unsigned short)(r >> 16);
}
__device__ __forceinline__ float bf2f(unsigned short h) {
    return __uint_as_float(((unsigned int)h) << 16);
}

// Wt[col][k] transposed+split from [Wst | Wq | Wk | Wv | Wu]
__global__ void wsplit_k(const float* __restrict__ Wst, const float* __restrict__ Wq,
                         const float* __restrict__ Wk, const float* __restrict__ Wv,
                         const float* __restrict__ Wu,
                         int K, int kshift, unsigned short* __restrict__ Whi,
                         unsigned short* __restrict__ Wlo) {
    int idx = blockIdx.x * 256 + threadIdx.x;
    if (idx >= NCOL * K) return;
    int col = idx >> kshift, k = idx & (K - 1);
    float w;
    if (col < 128)       w = Wst[k * 128 + col];
    else if (col < 640)  w = Wq[(size_t)k * 512 + col - 128];
    else if (col < 1152) w = Wk[(size_t)k * 512 + col - 640];
    else if (col < 1664) w = Wv[(size_t)k * 512 + col - 1152];
    else                 w = Wu[(size_t)k * 64 + col - 1664];
    unsigned short h = f2bf(w);
    Whi[idx] = h;
    Wlo[idx] = f2bf(w - bf2f(h));
}

// ---------------- fused S/Q/K/V/U GEMM via split-bf16 MFMA ----------------
// grid (27, N/64), block 256 (4 waves). Wave w: rows n0+w*16..+15, cols c0..c0+63.
// X read fp32 + split inline to registers; B staged in LDS in K-chunks of 64 (20 KB).
__global__ __launch_bounds__(256) void qkvs_mfma(
        const float* __restrict__ X, int K,
        const unsigned short* __restrict__ Whi, const unsigned short* __restrict__ Wlo,
        const float* __restrict__ bq, const float* __restrict__ bk,
        const float* __restrict__ bv, const float* __restrict__ bu,
        float* __restrict__ out, float* __restrict__ UB) {
    __shared__ __align__(16) unsigned short bs[2 * 64 * 80];   // 20 KB: hi/lo, 64 cols, 64k+pad
    const int ldb = 80, loHalf = 64 * 80;
    int tid = threadIdx.x;
    int wave = tid >> 6, lane = tid & 63;
    int m = lane & 15, kg = lane >> 4;
    int n0 = blockIdx.y * 64 + wave * 16;
    int c0 = blockIdx.x * 64;

    // ---- A fragments: load fp32 X, split hi/lo inline (all loads issued up-front) ----
    const float* xr = X + (size_t)(n0 + m) * K + kg * 8;
    short8 ahi[4], alo[4];
    int nkc = K >> 5;                       // 2 (K=64) or 4 (K=128)
#pragma unroll
    for (int kc = 0; kc < 4; ++kc) {
        if (kc < nkc) {
            float4 f0 = *(const float4*)(xr + kc * 32);
            float4 f1 = *(const float4*)(xr + kc * 32 + 4);
            float fv[8] = {f0.x, f0.y, f0.z, f0.w, f1.x, f1.y, f1.z, f1.w};
            short8 h, l;
#pragma unroll
            for (int j = 0; j < 8; ++j) {
                unsigned short hh = f2bf(fv[j]);
                h[j] = (short)hh;
                l[j] = (short)f2bf(fv[j] - bf2f(hh));
            }
            ahi[kc] = h;
            alo[kc] = l;
        }
    }

    float4v acc[4];
#pragma unroll
    for (int ct = 0; ct < 4; ++ct) acc[ct] = (float4v){0.f, 0.f, 0.f, 0.f};

    int nchunk = K >> 6;                    // 1 (K=64) or 2 (K=128)
    for (int ch = 0; ch < nchunk; ++ch) {
        if (ch) __syncthreads();            // drain previous chunk's reads
        // stage chunk: 64 cols x 64 k (hi+lo), coalesced
        for (int i = tid; i < 64 * 8; i += 256) {
            int col = i >> 3, part = i & 7;
            *(short8*)(bs + col * ldb + part * 8) =
                *(const short8*)(Whi + (size_t)(c0 + col) * K + ch * 64 + part * 8);
            *(short8*)(bs + loHalf + col * ldb + part * 8) =
                *(const short8*)(Wlo + (size_t)(c0 + col) * K + ch * 64 + part * 8);
        }
        __syncthreads();
#pragma unroll
        for (int kc2 = 0; kc2 < 2; ++kc2) {
            int kc = ch * 2 + kc2;
            if (kc >= nkc) break;
#pragma unroll
            for (int ct = 0; ct < 4; ++ct) {
                const unsigned short* bp = bs + (ct * 16 + m) * ldb + kg * 8 + kc2 * 32;
                short8 bhi = *(const short8*)(bp);
                short8 blo = *(const short8*)(bp + loHalf);
                acc[ct] = __builtin_amdgcn_mfma_f32_16x16x32_bf16(ahi[kc], bhi, acc[ct], 0, 0, 0);
                acc[ct] = __builtin_amdgcn_mfma_f32_16x16x32_bf16(alo[kc], bhi, acc[ct], 0, 0, 0);
                acc[ct] = __builtin_amdgcn_mfma_f32_16x16x32_bf16(ahi[kc], blo, acc[ct], 0, 0, 0);
            }
        }
    }

#pragma unroll
    for (int ct = 0; ct < 4; ++ct) {
        int col = c0 + ct * 16 + m;
        float bias;
        if (col < 128)       bias = 0.f;
        else if (col < 640)  bias = bq[col - 128];
        else if (col < 1152) bias = bk[col - 640];
        else if (col < 1664) bias = bv[col - 1152];
        else                 bias = bu[col - 1664];
#pragma unroll
        for (int r = 0; r < 4; ++r) {
            int row = n0 + kg * 4 + r;
            float v = acc[ct][r] + bias;
            if (col < 1664) out[(size_t)row * QLD + col] = v;
            else            UB[(size_t)row * 64 + col - 1664] = v;
        }
    }
}

// ---------------- outT GEMM: partials of O @ tW into K (y=0) and V (y=1) regions -------------
// y==0 additionally adds tnorm @ Wet (the deferred edge-feature term).
__global__ __launch_bounds__(64) void out_gemm(float* __restrict__ QB,
                                               const float* __restrict__ W,
                                               const float* __restrict__ TB,
                                               const float* __restrict__ Wet) {
    const int ROWS = 16, PAD = 20, KC = 128;
    __shared__ __align__(16) float xs[KC * PAD];
    __shared__ __align__(16) float ts[64 * PAD];
    int tid = threadIdx.x;        // 64
    int n0 = blockIdx.x * ROWS;
    int kb = blockIdx.y * 256;
    int oo = blockIdx.y ? 1152 : 640;
    float acc0[ROWS], acc1[ROWS];
#pragma unroll
    for (int r = 0; r < ROWS; ++r) { acc0[r] = 0.f; acc1[r] = 0.f; }
    const float* wp0 = W + (size_t)kb * 128 + tid;
    const float* wp1 = wp0 + 64;
    for (int k0 = 0; k0 < 256; k0 += KC) {
        for (int i = tid; i < ROWS * KC; i += 64) {
            int kk = i & 127, r = i >> 7;
            xs[kk * PAD + r] = QB[(size_t)(n0 + r) * QLD + 128 + kb + k0 + kk];
        }
        __syncthreads();
#pragma unroll 4
        for (int kk = 0; kk < KC; ++kk) {
            const float* xr = xs + kk * PAD;
            float xv[ROWS];
            float4* xvv = (float4*)xv;
            xvv[0] = *(const float4*)(xr);
            xvv[1] = *(const float4*)(xr + 4);
            xvv[2] = *(const float4*)(xr + 8);
            xvv[3] = *(const float4*)(xr + 12);
            float w0 = *wp0; wp0 += 128;
            float w1 = *wp1; wp1 += 128;
#pragma unroll
            for (int r = 0; r < ROWS; ++r) {
                acc0[r] = fmaf(xv[r], w0, acc0[r]);
                acc1[r] = fmaf(xv[r], w1, acc1[r]);
            }
        }
        __syncthreads();
    }
    if (blockIdx.y == 0) {
        for (int i = tid; i < ROWS * 64; i += 64) {
            int r = i >> 6, j = i & 63;
            ts[j * PAD + r] = TB[(size_t)(n0 + r) * 64 + j];
        }
        __syncthreads();
#pragma unroll 4
        for (int j = 0; j < 64; ++j) {
            const float* tr = ts + j * PAD;
            float xv[ROWS];
            float4* xvv = (float4*)xv;
            xvv[0] = *(const float4*)(tr);
            xvv[1] = *(const float4*)(tr + 4);
            xvv[2] = *(const float4*)(tr + 8);
            xvv[3] = *(const float4*)(tr + 12);
            float w0 = Wet[j * 128 + tid];
            float w1 = Wet[j * 128 + tid + 64];
#pragma unroll
            for (int r = 0; r < ROWS; ++r) {
                acc0[r] = fmaf(xv[r], w0, acc0[r]);
                acc1[r] = fmaf(xv[r], w1, acc1[r]);
            }
        }
    }
#pragma unroll
    for (int r = 0; r < ROWS; ++r) {
        QB[(size_t)(n0 + r) * QLD + oo + tid]      = acc0[r];
        QB[(size_t)(n0 + r) * QLD + oo + tid + 64] = acc1[r];
    }
}

// ---------------- per-layer weight prep (warp per output) ----------------
__global__ void prep_k(const float* __restrict__ Ws, const float* __restrict__ bs,
                       const float* __restrict__ tW, const float* __restrict__ Wb,
                       const float* __restrict__ Wq, const float* __restrict__ bq,
                       const float* __restrict__ We, int Fin,
                       float* __restrict__ Wst, float* __restrict__ ws_z,
                       float* __restrict__ sbt, float* __restrict__ zb,
                       float* __restrict__ Wu, float* __restrict__ bu,
                       float* __restrict__ Wet, float* __restrict__ wez) {
    int w = (blockIdx.x * blockDim.x + threadIdx.x) >> 6;
    int lane = threadIdx.x & 63;
    int nW = Fin * 128;
    int o1 = nW, o2 = o1 + Fin, o3 = o2 + 128, o4 = o3 + 1;
    int o5 = o4 + Fin * 64, o6 = o5 + 64, o7 = o6 + 8192, total = o7 + 64;
    if (w >= total) return;
    float s = 0.f;
    if (w < o1) {
        int f = w >> 7, m = w & 127;
        for (int c = lane; c < 512; c += 64)
            s = fmaf(Ws[(size_t)f * 512 + c], tW[(size_t)c * 128 + m], s);
    } else if (w < o2) {
        int f = w - o1;
        for (int c = lane; c < 512; c += 64)
            s = fmaf(Ws[(size_t)f * 512 + c], Wb[512 + c] - Wb[1024 + c], s);
    } else if (w < o3) {
        int m = w - o2;
        for (int c = lane; c < 512; c += 64)
            s = fmaf(bs[c], tW[(size_t)c * 128 + m], s);
    } else if (w < o4) {
        for (int c = lane; c < 512; c += 64)
            s = fmaf(bs[c], Wb[512 + c] - Wb[1024 + c], s);
    } else if (w < o5) {   // Wu
        int q = w - o4; int f = q >> 6; int j2 = q & 63;
        int j = j2 & 15; int cb = (j2 >> 4) * 128;
        s = Wq[(size_t)f * 512 + cb + lane] * We[j * 512 + cb + lane]
          + Wq[(size_t)f * 512 + cb + lane + 64] * We[j * 512 + cb + lane + 64];
    } else if (w < o6) {   // bu
        int j2 = w - o5; int j = j2 & 15; int cb = (j2 >> 4) * 128;
        s = bq[cb + lane] * We[j * 512 + cb + lane]
          + bq[cb + lane + 64] * We[j * 512 + cb + lane + 64];
    } else if (w < o7) {   // Wet
        int q = w - o6; int j2 = q >> 7; int m = q & 127;
        int j = j2 & 15; int cb = (j2 >> 4) * 128;
        s = We[j * 512 + cb + lane] * tW[(size_t)(cb + lane) * 128 + m]
          + We[j * 512 + cb + lane + 64] * tW[(size_t)(cb + lane + 64) * 128 + m];
    } else {               // wez
        int j2 = w - o7; int j = j2 & 15; int cb = (j2 >> 4) * 128;
        s = We[j * 512 + cb + lane] * (Wb[cb + lane] + Wb[1024 + cb + lane])
          + We[j * 512 + cb + lane + 64] * (Wb[cb + lane + 64] + Wb[1024 + cb + lane + 64]);
    }
#pragma unroll
    for (int off = 32; off; off >>= 1) s += __shfl_xor(s, off, 64);
    if (lane == 0) {
        if (w < o1) Wst[w] = s;
        else if (w < o2) ws_z[w - o1] = s;
        else if (w < o3) sbt[w - o2] = s;
        else if (w < o4) zb[0] = s;
        else if (w < o5) Wu[w - o4] = s;
        else if (w < o6) bu[w - o5] = s;
        else if (w < o7) Wet[w - o6] = s;
        else wez[w - o7] = s;
    }
}

// ---------------- per-graph CSR build (edges of graph g are [g*512,(g+1)*512)) --------------
__global__ __launch_bounds__(128) void csr_graph_k(const int* __restrict__ src,
                                                   const int* __restrict__ dst,
                                                   int* __restrict__ row_start,
                                                   int* __restrict__ row_end,
                                                   int* __restrict__ colb,
                                                   int* __restrict__ eidb) {
    __shared__ int cnt[128], pref[128], cur[128];
    int g = blockIdx.x, t = threadIdx.x;
    cnt[t] = 0;
    __syncthreads();
    int e0 = g * 512, nb = g * 128;
    int dl[4], sl[4];
#pragma unroll
    for (int i = 0; i < 4; ++i) {
        int e = e0 + t + i * 128;
        dl[i] = dst[e] - nb;
        sl[i] = src[e];
        atomicAdd(&cnt[dl[i]], 1);
    }
    __syncthreads();
    pref[t] = cnt[t];
    __syncthreads();
    for (int st = 1; st < 128; st <<= 1) {
        int v = (t >= st) ? pref[t - st] : 0;
        __syncthreads();
        pref[t] += v;
        __syncthreads();
    }
    int ex = pref[t] - cnt[t];
    row_start[nb + t] = e0 + ex;
    row_end[nb + t]   = e0 + pref[t];
    cur[t] = ex;
    __syncthreads();
#pragma unroll
    for (int i = 0; i < 4; ++i) {
        int pos = atomicAdd(&cur[dl[i]], 1);
        colb[e0 + pos] = sl[i];
        eidb[e0 + pos] = e0 + t + i * 128;
    }
}

// ---------------- attention: U/T decomposition, no LDS, plain-exp softmax ----------------
__global__ __launch_bounds__(256) void attn_k(
        float* __restrict__ QB, const float* __restrict__ UB, float* __restrict__ TB,
        const int* __restrict__ row_start, const int* __restrict__ row_end,
        const int* __restrict__ colb, const int* __restrict__ eidb,
        const float* __restrict__ ea, const float* __restrict__ Wb,
        const float* __restrict__ wez, float* __restrict__ zOut4) {
    int tid = threadIdx.x;
    int head = tid >> 6, lane = tid & 63;
    int c0 = head * 128 + lane, c1 = c0 + 64;
    float w13a = Wb[c0] + Wb[1024 + c0];
    float w13b = Wb[c1] + Wb[1024 + c1];
    float wezv = (lane < 16) ? wez[head * 16 + lane] : 0.f;
    int nodeBase = blockIdx.x * 4;
    float o0v[4], o1v[4], tnv[4], zpv[4];
#pragma unroll
    for (int rr = 0; rr < 4; ++rr) {
        int node = nodeBase + rr;
        const float* Qr = QB + (size_t)node * QLD + 128;
        float q0 = Qr[c0], q1 = Qr[c1];
        float uu = (lane < 16) ? UB[(size_t)node * 64 + head * 16 + lane] : 0.f;
        float l = 0.f, a0 = 0.f, a1 = 0.f, t = 0.f;
        int beg = row_start[node], end = row_end[node];
        for (int j = beg; j < end; ++j) {
            int s = colb[j];
            int e = eidb[j];
            const float* Kr = QB + (size_t)s * QLD + 640;
            const float* Vr = QB + (size_t)s * QLD + 1152;
            float k0 = Kr[c0], k1 = Kr[c1];
            float v0 = Vr[c0], v1 = Vr[c1];
            float eav = (lane < 16) ? ea[(size_t)e * 16 + lane] : 0.f;
            float part = q0 * k0 + q1 * k1 + eav * uu;
#pragma unroll
            for (int off = 32; off; off >>= 1) part += __shfl_xor(part, off, 64);
            float w = expf(part * 0.08838834764831845f);  // 1/sqrt(128); alpha O(10), safe
            l += w;
            a0 = fmaf(w, v0, a0);
            a1 = fmaf(w, v1, a1);
            t  = fmaf(w, eav, t);
        }
        float inv = 1.f / (l + 1e-16f);
        o0v[rr] = a0 * inv;
        o1v[rr] = a1 * inv;
        tnv[rr] = t * inv;
        float zp = o0v[rr] * w13a + o1v[rr] * w13b + tnv[rr] * wezv;
#pragma unroll
        for (int off = 32; off; off >>= 1) zp += __shfl_xor(zp, off, 64);
        zpv[rr] = zp;
    }
#pragma unroll
    for (int rr = 0; rr < 4; ++rr) {
        int node = nodeBase + rr;
        float* Qr = QB + (size_t)node * QLD + 128;
        Qr[c0] = o0v[rr];
        Qr[c1] = o1v[rr];
        if (lane < 16) TB[(size_t)node * 64 + head * 16 + lane] = tnv[rr];
        if (lane == 0) zOut4[node * 4 + head] = zpv[rr];
    }
}

// ---------------- combine: x_next = relu(beta*(skipT+sbt) + (1-beta)*outT + tb) -------------
__global__ void combine_k(const float* __restrict__ x, int Fin,
                          const float* __restrict__ ws_z, const float* __restrict__ zb,
                          const float* __restrict__ zOut4, const float* __restrict__ B,
                          const float* __restrict__ sbt, const float* __restrict__ tb,
                          float* __restrict__ xn) {
    __shared__ float red[128];
    int node = blockIdx.x, t = threadIdx.x;  // 128
    red[t] = (t < Fin) ? x[(size_t)node * Fin + t] * ws_z[t] : 0.f;
    __syncthreads();
    for (int st = 64; st; st >>= 1) {
        if (t < st) red[t] += red[t + st];
        __syncthreads();
    }
    float z = zOut4[node * 4] + zOut4[node * 4 + 1] + zOut4[node * 4 + 2] + zOut4[node * 4 + 3]
            + red[0] + zb[0];
    float beta = 1.f / (1.f + expf(-z));
    const float* row = B + (size_t)node * QLD;
    float outT = row[640 + t] + row[1152 + t];
    float a = beta * (row[t] + sbt[t]) + (1.f - beta) * outT + tb[t];
    xn[(size_t)node * 128 + t] = fmaxf(a, 0.f);
}

// ---------------- batchnorm ----------------
__global__ void bn_stats_k(const float* __restrict__ x, int N, float* __restrict__ stats) {
    int c = threadIdx.x;  // 128
    float s = 0.f, ss = 0.f;
    for (int n = blockIdx.x; n < N; n += gridDim.x) {
        float v = x[(size_t)n * 128 + c];
        s += v; ss += v * v;
    }
    atomicAdd(&stats[c], s);
    atomicAdd(&stats[128 + c], ss);
}

__global__ void bn_apply_k(float* __restrict__ x, int N, const float* __restrict__ stats,
                           const float* __restrict__ g, const float* __restrict__ b) {
    int idx = blockIdx.x * blockDim.x + threadIdx.x;
    if (idx >= N * 128) return;
    int c = idx & 127;
    float m = stats[c] / (float)N;
    float var = fmaxf(stats[128 + c] / (float)N - m * m, 0.f);
    float inv = rsqrtf(var + 1e-5f);
    x[idx] = g[c] * (x[idx] - m) * inv + b[c];
}

// bn apply + pooling score in one pass (wave = node). grid N/4, block 256.
__global__ void bn_apply_score_k(float* __restrict__ x, int N, const float* __restrict__ stats,
                                 const float* __restrict__ g, const float* __restrict__ b,
                                 const float* __restrict__ w, float* __restrict__ s) {
    int node = blockIdx.x * 4 + (threadIdx.x >> 6);
    int lane = threadIdx.x & 63;
    int c0 = lane, c1 = lane + 64;
    float m0 = stats[c0] / (float)N;
    float v0 = fmaxf(stats[128 + c0] / (float)N - m0 * m0, 0.f);
    float m1 = stats[c1] / (float)N;
    float v1 = fmaxf(stats[128 + c1] / (float)N - m1 * m1, 0.f);
    float* row = x + (size_t)node * 128;
    float x0 = g[c0] * (row[c0] - m0) * rsqrtf(v0 + 1e-5f) + b[c0];
    float x1 = g[c1] * (row[c1] - m1) * rsqrtf(v1 + 1e-5f) + b[c1];
    row[c0] = x0;
    row[c1] = x1;
    float w0 = w[c0], w1 = w[c1];
    float p  = x0 * w0 + x1 * w1;
    float nw = w0 * w0 + w1 * w1;
#pragma unroll
    for (int off = 32; off; off >>= 1) {
        p  += __shfl_xor(p, off, 64);
        nw += __shfl_xor(nw, off, 64);
    }
    if (lane == 0) s[node] = p / sqrtf(nw);
}

// ---------------- pool0: topk + gather + readout + per-graph CSR rebuild --------------------
__global__ __launch_bounds__(128) void topk_pool0_k(
        const float* __restrict__ sc, const float* __restrict__ x,
        const int* __restrict__ src, const int* __restrict__ dst,
        float* __restrict__ xp, float* __restrict__ rep,
        int* __restrict__ row_start, int* __restrict__ row_end,
        int* __restrict__ colb, int* __restrict__ eidb) {
    __shared__ float ls[128], th[64];
    __shared__ int lk[128], rk[128], oon[64];
    __shared__ int cnt[64], pref[64], cur[64];
    int g = blockIdx.x, t = threadIdx.x;
    float val = sc[g * 128 + t];
    ls[t] = val;
    __syncthreads();
    int c = 0;
    for (int j = 0; j < 128; ++j) {
        float vj = ls[j];
        c += (vj > val || (vj == val && j < t)) ? 1 : 0;
    }
    int kp = (c < 64) ? 1 : 0;
    lk[t] = kp;
    __syncthreads();
    int r = 0;
    for (int j = 0; j < t; ++j) r += lk[j];
    rk[t] = r;
    if (kp) { oon[r] = t; th[r] = tanhf(val); }
    __syncthreads();
    float mx = -INFINITY, sm = 0.f;
    for (int rr = 0; rr < 64; ++rr) {
        float v = x[(size_t)(g * 128 + oon[rr]) * 128 + t] * th[rr];
        xp[(size_t)(g * 64 + rr) * 128 + t] = v;
        mx = fmaxf(mx, v);
        sm += v;
    }
    rep[g * 256 + t] = mx;
    rep[g * 256 + 128 + t] = sm * (1.f / 64.f);
    if (t < 64) cnt[t] = 0;
    __syncthreads();
    int e0 = g * 512, nb = g * 128;
    int keepE[4], dr[4], sr[4];
#pragma unroll
    for (int i = 0; i < 4; ++i) {
        int e = e0 + t + i * 128;
        int s_ = src[e] - nb, d_ = dst[e] - nb;
        int ke = lk[s_] && lk[d_];
        keepE[i] = ke;
        dr[i] = rk[d_];
        sr[i] = rk[s_];
        if (ke) atomicAdd(&cnt[dr[i]], 1);
    }
    __syncthreads();
    if (t < 64) pref[t] = cnt[t];
    __syncthreads();
    for (int st = 1; st < 64; st <<= 1) {
        int v = (t < 64 && t >= st) ? pref[t - st] : 0;
        __syncthreads();
        if (t < 64) pref[t] += v;
        __syncthreads();
    }
    if (t < 64) {
        int ex = pref[t] - cnt[t];
        row_start[g * 64 + t] = e0 + ex;
        row_end[g * 64 + t]   = e0 + pref[t];
        cur[t] = ex;
    }
    __syncthreads();
#pragma unroll
    for (int i = 0; i < 4; ++i) {
        if (keepE[i]) {
            int pos = atomicAdd(&cur[dr[i]], 1);
            colb[e0 + pos] = g * 64 + sr[i];
            eidb[e0 + pos] = e0 + t + i * 128;
        }
    }
}

// ---------------- pool1: topk + readout only. n=64 -> k=32. block 128. ----------------------
__global__ __launch_bounds__(128) void topk_pool1_k(
        const float* __restrict__ sc, const float* __restrict__ x,
        float* __restrict__ rep) {
    __shared__ float ls[64], th[32];
    __shared__ int lk[64], oon[32];
    int g = blockIdx.x, t = threadIdx.x;
    float val = 0.f;
    if (t < 64) { val = sc[g * 64 + t]; ls[t] = val; }
    __syncthreads();
    if (t < 64) {
        int c = 0;
        for (int j = 0; j < 64; ++j) {
            float vj = ls[j];
            c += (vj > val || (vj == val && j < t)) ? 1 : 0;
        }
        int kp = (c < 32) ? 1 : 0;
        lk[t] = kp;
    }
    __syncthreads();
    if (t < 64 && lk[t]) {
        int r = 0;
        for (int j = 0; j < t; ++j) r += lk[j];
        oon[r] = t;
        th[r] = tanhf(val);
    }
    __syncthreads();
    float mx = -INFINITY, sm = 0.f;
    for (int rr = 0; rr < 32; ++rr) {
        float v = x[(size_t)(g * 64 + oon[rr]) * 128 + t] * th[rr];
        mx = fmaxf(mx, v);
        sm += v;
    }
    rep[g * 256 + t] = mx;
    rep[g * 256 + 128 + t] = sm * (1.f / 32.f);
}

// ---------------- MLP head: one block per graph, fp32 output ----------------
__global__ void head_k(const float* __restrict__ rep0, const float* __restrict__ rep1,
                       const float* __restrict__ W1, const float* __restrict__ b1,
                       const float* __restrict__ W2, const float* __restrict__ b2,
                       const float* __restrict__ W3, const float* __restrict__ b3,
                       float* __restrict__ out) {
    __shared__ float h[256], a1[256], a2[128], red[256];
    int g = blockIdx.x, t = threadIdx.x;  // 256
    h[t] = rep0[g * 256 + t] + rep1[g * 256 + t];
    __syncthreads();
    float acc = b1[t];
    for (int i = 0; i < 256; ++i) acc = fmaf(h[i], W1[i * 256 + t], acc);
    a1[t] = fmaxf(acc, 0.f);
    __syncthreads();
    if (t < 128) {
        float a = b2[t];
        for (int i = 0; i < 256; ++i) a = fmaf(a1[i], W2[i * 128 + t], a);
        a2[t] = fmaxf(a, 0.f);
    }
    __syncthreads();
    red[t] = (t < 128) ? a2[t] * W3[t] : 0.f;
    __syncthreads();
    for (int st = 128; st; st >>= 1) {
        if (t < st) red[t] += red[t + st];
        __syncthreads();
    }
    if (t == 0) out[g] = red[0] + b3[0];
}

// ======================================================================================
extern "C" void kernel_launch(void* const* d_in, const int* in_sizes, int n_in,
                              void* d_out, int out_size, void* d_ws, size_t ws_size,
                              hipStream_t stream) {
    (void)in_sizes; (void)n_in; (void)out_size; (void)ws_size;

    const float* x0    = (const float*)d_in[0];
    const int*   ei    = (const int*)d_in[1];
    const float* ea    = (const float*)d_in[2];
    const float* c1_Wq = (const float*)d_in[3];
    const float* c1_bq = (const float*)d_in[4];
    const float* c1_Wk = (const float*)d_in[5];
    const float* c1_bk = (const float*)d_in[6];
    const float* c1_Wv = (const float*)d_in[7];
    const float* c1_bv = (const float*)d_in[8];
    const float* c1_We = (const float*)d_in[9];
    const float* c1_Ws = (const float*)d_in[10];
    const float* c1_bs = (const float*)d_in[11];
    const float* c1_Wb = (const float*)d_in[12];
    const float* t1_W  = (const float*)d_in[13];
    const float* t1_b  = (const float*)d_in[14];
    const float* bn1_g = (const float*)d_in[15];
    const float* bn1_b = (const float*)d_in[16];
    const float* cl_Wq = (const float*)d_in[17];
    const float* cl_bq = (const float*)d_in[18];
    const float* cl_Wk = (const float*)d_in[19];
    const float* cl_bk = (const float*)d_in[20];
    const float* cl_Wv = (const float*)d_in[21];
    const float* cl_bv = (const float*)d_in[22];
    const float* cl_We = (const float*)d_in[23];
    const float* cl_Ws = (const float*)d_in[24];
    const float* cl_bs = (const float*)d_in[25];
    const float* cl_Wb = (const float*)d_in[26];
    const float* tl_W  = (const float*)d_in[27];
    const float* tl_b  = (const float*)d_in[28];
    const float* bnl_g = (const float*)d_in[29];
    const float* bnl_b = (const float*)d_in[30];
    const float* pool_w= (const float*)d_in[31];
    const float* l1_W  = (const float*)d_in[32];
    const float* l1_b  = (const float*)d_in[33];
    const float* l2_W  = (const float*)d_in[34];
    const float* l2_b  = (const float*)d_in[35];
    const float* l3_W  = (const float*)d_in[36];
    const float* l3_b  = (const float*)d_in[37];
    float* out = (float*)d_out;

    // -------- workspace layout (~128 MB) --------
    char* base = (char*)d_ws;
    size_t off = 0;
    auto alloc = [&](size_t bytes) -> void* {
        void* p = base + off;
        off += (bytes + 255) & ~(size_t)255;
        return p;
    };
    float* QB   = (float*)alloc((size_t)16384 * QLD * 4);   // 109 MB
    float* xA   = (float*)alloc((size_t)16384 * 128 * 4);
    float* xB   = (float*)alloc((size_t)16384 * 128 * 4);
    float* zOut4= (float*)alloc((size_t)16384 * 4 * 4);
    float* Wst  = (float*)alloc(128 * 128 * 4);
    float* ws_z = (float*)alloc(128 * 4);
    float* sbt  = (float*)alloc(128 * 4);
    float* zb   = (float*)alloc(4 * 4);
    float* Wu   = (float*)alloc(128 * 64 * 4);
    float* bu   = (float*)alloc(64 * 4);
    float* Wet  = (float*)alloc(64 * 128 * 4);
    float* wez  = (float*)alloc(64 * 4);
    float* stats  = (float*)alloc(256 * 4);
    float* scores = (float*)alloc(16384 * 4);
    float* rep0   = (float*)alloc(128 * 256 * 4);
    float* rep1   = (float*)alloc(128 * 256 * 4);
    int* row_start = (int*)alloc(16384 * 4);
    int* row_end   = (int*)alloc(16384 * 4);
    int* colb      = (int*)alloc(E_TOT * 4);
    int* eidb      = (int*)alloc(E_TOT * 4);
    unsigned short* Whi = (unsigned short*)alloc((size_t)NCOL * 128 * 2);
    unsigned short* Wlo = (unsigned short*)alloc((size_t)NCOL * 128 * 2);
    float* xp = xA;           // alias: xA dead once loop-0's combine has consumed it
    float* UB = xB;           // alias: U lives in xB's first half during a tconv
    float* TB = xB + (size_t)16384 * 64;  // alias: T in xB's second half (dead before combine)

    // Full tconv + t-layer(+bias+relu): xn = relu(gated @ tW + tb)
    auto tconv = [&](const float* xin, int N, int Fin,
                     const float* Wq, const float* bq, const float* Wk, const float* bk,
                     const float* Wv, const float* bv, const float* We,
                     const float* Ws, const float* bs, const float* Wb,
                     const float* tW, const float* tb, float* xn) {
        int total = Fin * 128 + Fin + 129 + Fin * 64 + 64 + 8192 + 64;
        prep_k<<<(total + 3) / 4, 256, 0, stream>>>(Ws, bs, tW, Wb, Wq, bq, We, Fin,
                                                    Wst, ws_z, sbt, zb, Wu, bu, Wet, wez);
        int kshift = (Fin == 64) ? 6 : 7;
        wsplit_k<<<(NCOL * Fin + 255) / 256, 256, 0, stream>>>(Wst, Wq, Wk, Wv, Wu,
                                                               Fin, kshift, Whi, Wlo);
        qkvs_mfma<<<dim3(27, N / 64), 256, 0, stream>>>(xin, Fin, Whi, Wlo,
                                                        bq, bk, bv, bu, QB, UB);
        attn_k<<<N / 4, 256, 0, stream>>>(QB, UB, TB, row_start, row_end, colb, eidb,
                                          ea, Wb, wez, zOut4);
        out_gemm<<<dim3(N / 16, 2), 64, 0, stream>>>(QB, tW, TB, Wet);
        combine_k<<<N, 128, 0, stream>>>(xin, Fin, ws_z, zb, zOut4, QB, sbt, tb, xn);
    };

    // ---- CSR over original edges (per-graph, one kernel) ----
    csr_graph_k<<<B_G, 128, 0, stream>>>(ei, ei + E_TOT, row_start, row_end, colb, eidb);

    // ---- layer 1: tconv(Fin=64) + t1 + bn1 ----
    tconv(x0, 16384, 64, c1_Wq, c1_bq, c1_Wk, c1_bk, c1_Wv, c1_bv, c1_We,
          c1_Ws, c1_bs, c1_Wb, t1_W, t1_b, xA);
    hipMemsetAsync(stats, 0, 256 * 4, stream);
    bn_stats_k<<<128, 128, 0, stream>>>(xA, 16384, stats);
    bn_apply_k<<<(16384 * 128 + 255) / 256, 256, 0, stream>>>(xA, 16384, stats, bn1_g, bn1_b);

    // ---- loop layer 0 (Fin=128, N=16384) ----
    tconv(xA, 16384, 128, cl_Wq, cl_bq, cl_Wk, cl_bk, cl_Wv, cl_bv, cl_We,
          cl_Ws, cl_bs, cl_Wb, tl_W, tl_b, xB);
    hipMemsetAsync(stats, 0, 256 * 4, stream);
    bn_stats_k<<<128, 128, 0, stream>>>(xB, 16384, stats);
    bn_apply_score_k<<<16384 / 4, 256, 0, stream>>>(xB, 16384, stats, bnl_g, bnl_b,
                                                    pool_w, scores);

    // ---- pool 0 (fused topk+gather+readout+CSR) ----
    topk_pool0_k<<<B_G, 128, 0, stream>>>(scores, xB, ei, ei + E_TOT, xp, rep0,
                                          row_start, row_end, colb, eidb);

    // ---- loop layer 1 (Fin=128, N=8192) ----
    tconv(xp, 8192, 128,
          cl_Wq + 65536, cl_bq + 512, cl_Wk + 65536, cl_bk + 512,
          cl_Wv + 65536, cl_bv + 512, cl_We + 8192,
          cl_Ws + 65536, cl_bs + 512, cl_Wb + 1536,
          tl_W + 65536, tl_b + 128, xB);
    hipMemsetAsync(stats, 0, 256 * 4, stream);
    bn_stats_k<<<128, 128, 0, stream>>>(xB, 8192, stats);
    bn_apply_score_k<<<8192 / 4, 256, 0, stream>>>(xB, 8192, stats, bnl_g + 128, bnl_b + 128,
                                                   pool_w + 128, scores);

    // ---- pool 1 (fused topk+readout) ----
    topk_pool1_k<<<B_G, 128, 0, stream>>>(scores, xB, rep1);

    // ---- MLP head (fp32 out) ----
    head_k<<<B_G, 256, 0, stream>>>(rep0, rep1, l1_W, l1_b, l2_W, l2_b, l3_W, l3_b, out);
}

// Round 14
// 737.280 us; speedup vs baseline: 1.6550x; 1.6550x over previous
//
#include <hip/hip_runtime.h>
#include <math.h>

#define E_TOT 65536
#define B_G   128
#define QLD   1664   // fused buffer row: [S(128) | Q/O(512) | K/outT0(512) | V/outT1(512)]
#define NCOL  1728   // GEMM cols: QLD + 64 (U = We^T q projection)

typedef __attribute__((ext_vector_type(8))) short short8;
typedef __attribute__((ext_vector_type(4))) float float4v;

__device__ __forceinline__ unsigned short f2bf(float f) {
    unsigned int u = __float_as_uint(f);
    unsigned int r = u + 0x7FFFu + ((u >> 16) & 1u);   // round-to-nearest-even
    return (unsigned short)(r >> 16);
}
__device__ __forceinline__ float bf2f(unsigned short h) {
    return __uint_as_float(((unsigned int)h) << 16);
}

// Wt[col][k] transposed+split from [Wst | Wq | Wk | Wv | Wu]
__global__ void wsplit_k(const float* __restrict__ Wst, const float* __restrict__ Wq,
                         const float* __restrict__ Wk, const float* __restrict__ Wv,
                         const float* __restrict__ Wu,
                         int K, int kshift, unsigned short* __restrict__ Whi,
                         unsigned short* __restrict__ Wlo) {
    int idx = blockIdx.x * 256 + threadIdx.x;
    if (idx >= NCOL * K) return;
    int col = idx >> kshift, k = idx & (K - 1);
    float w;
    if (col < 128)       w = Wst[k * 128 + col];
    else if (col < 640)  w = Wq[(size_t)k * 512 + col - 128];
    else if (col < 1152) w = Wk[(size_t)k * 512 + col - 640];
    else if (col < 1664) w = Wv[(size_t)k * 512 + col - 1152];
    else                 w = Wu[(size_t)k * 64 + col - 1664];
    unsigned short h = f2bf(w);
    Whi[idx] = h;
    Wlo[idx] = f2bf(w - bf2f(h));
}

// ---------------- fused S/Q/K/V/U GEMM via split-bf16 MFMA (fully static loops) --------------
// grid (27, N/64), block 256 (4 waves). Wave w: rows n0+w*16..+15, cols c0..c0+63.
// X read fp32 + split inline; B staged in LDS in K-chunks of 64 (20 KB).
// ALL register arrays indexed by compile-time constants (KT template param).
template <int KT>
__global__ __launch_bounds__(256) void qkvs_mfma(
        const float* __restrict__ X,
        const unsigned short* __restrict__ Whi, const unsigned short* __restrict__ Wlo,
        const float* __restrict__ bq, const float* __restrict__ bk,
        const float* __restrict__ bv, const float* __restrict__ bu,
        float* __restrict__ out, float* __restrict__ UB) {
    constexpr int NKC = KT >> 5;            // 2 (K=64) or 4 (K=128)
    constexpr int NCH = KT >> 6;            // 1 or 2
    __shared__ __align__(16) unsigned short bs[2 * 64 * 80];   // 20 KB
    const int ldb = 80, loHalf = 64 * 80;
    int tid = threadIdx.x;
    int wave = tid >> 6, lane = tid & 63;
    int m = lane & 15, kg = lane >> 4;
    int n0 = blockIdx.y * 64 + wave * 16;
    int c0 = blockIdx.x * 64;

    // ---- A fragments: load fp32 X, split hi/lo inline (static unroll) ----
    const float* xr = X + (size_t)(n0 + m) * KT + kg * 8;
    short8 ahi[NKC], alo[NKC];
#pragma unroll
    for (int kc = 0; kc < NKC; ++kc) {
        float4 f0 = *(const float4*)(xr + kc * 32);
        float4 f1 = *(const float4*)(xr + kc * 32 + 4);
        float fv0 = f0.x, fv1 = f0.y, fv2 = f0.z, fv3 = f0.w;
        float fv4 = f1.x, fv5 = f1.y, fv6 = f1.z, fv7 = f1.w;
        unsigned short h0 = f2bf(fv0), h1 = f2bf(fv1), h2 = f2bf(fv2), h3 = f2bf(fv3);
        unsigned short h4 = f2bf(fv4), h5 = f2bf(fv5), h6 = f2bf(fv6), h7 = f2bf(fv7);
        short8 h = {(short)h0, (short)h1, (short)h2, (short)h3,
                    (short)h4, (short)h5, (short)h6, (short)h7};
        short8 l = {(short)f2bf(fv0 - bf2f(h0)), (short)f2bf(fv1 - bf2f(h1)),
                    (short)f2bf(fv2 - bf2f(h2)), (short)f2bf(fv3 - bf2f(h3)),
                    (short)f2bf(fv4 - bf2f(h4)), (short)f2bf(fv5 - bf2f(h5)),
                    (short)f2bf(fv6 - bf2f(h6)), (short)f2bf(fv7 - bf2f(h7))};
        ahi[kc] = h;
        alo[kc] = l;
    }

    float4v acc[4];
#pragma unroll
    for (int ct = 0; ct < 4; ++ct) acc[ct] = (float4v){0.f, 0.f, 0.f, 0.f};

#pragma unroll
    for (int ch = 0; ch < NCH; ++ch) {
        if (ch) __syncthreads();            // drain previous chunk's reads
        // stage chunk: 64 cols x 64 k (hi+lo), coalesced
        for (int i = tid; i < 64 * 8; i += 256) {
            int col = i >> 3, part = i & 7;
            *(short8*)(bs + col * ldb + part * 8) =
                *(const short8*)(Whi + (size_t)(c0 + col) * KT + ch * 64 + part * 8);
            *(short8*)(bs + loHalf + col * ldb + part * 8) =
                *(const short8*)(Wlo + (size_t)(c0 + col) * KT + ch * 64 + part * 8);
        }
        __syncthreads();
#pragma unroll
        for (int kc2 = 0; kc2 < 2; ++kc2) {
            const int kc = ch * 2 + kc2;    // compile-time (both loops unrolled)
#pragma unroll
            for (int ct = 0; ct < 4; ++ct) {
                const unsigned short* bp = bs + (ct * 16 + m) * ldb + kg * 8 + kc2 * 32;
                short8 bhi = *(const short8*)(bp);
                short8 blo = *(const short8*)(bp + loHalf);
                acc[ct] = __builtin_amdgcn_mfma_f32_16x16x32_bf16(ahi[kc], bhi, acc[ct], 0, 0, 0);
                acc[ct] = __builtin_amdgcn_mfma_f32_16x16x32_bf16(alo[kc], bhi, acc[ct], 0, 0, 0);
                acc[ct] = __builtin_amdgcn_mfma_f32_16x16x32_bf16(ahi[kc], blo, acc[ct], 0, 0, 0);
            }
        }
    }

#pragma unroll
    for (int ct = 0; ct < 4; ++ct) {
        int col = c0 + ct * 16 + m;
        float bias;
        if (col < 128)       bias = 0.f;
        else if (col < 640)  bias = bq[col - 128];
        else if (col < 1152) bias = bk[col - 640];
        else if (col < 1664) bias = bv[col - 1152];
        else                 bias = bu[col - 1664];
#pragma unroll
        for (int r = 0; r < 4; ++r) {
            int row = n0 + kg * 4 + r;
            float v = acc[ct][r] + bias;
            if (col < 1664) out[(size_t)row * QLD + col] = v;
            else            UB[(size_t)row * 64 + col - 1664] = v;
        }
    }
}

// ---------------- outT GEMM: partials of O @ tW into K (y=0) and V (y=1) regions -------------
// y==0 additionally adds tnorm @ Wet (the deferred edge-feature term).
__global__ __launch_bounds__(64) void out_gemm(float* __restrict__ QB,
                                               const float* __restrict__ W,
                                               const float* __restrict__ TB,
                                               const float* __restrict__ Wet) {
    const int ROWS = 16, PAD = 20, KC = 128;
    __shared__ __align__(16) float xs[KC * PAD];
    __shared__ __align__(16) float ts[64 * PAD];
    int tid = threadIdx.x;        // 64
    int n0 = blockIdx.x * ROWS;
    int kb = blockIdx.y * 256;
    int oo = blockIdx.y ? 1152 : 640;
    float acc0[ROWS], acc1[ROWS];
#pragma unroll
    for (int r = 0; r < ROWS; ++r) { acc0[r] = 0.f; acc1[r] = 0.f; }
    const float* wp0 = W + (size_t)kb * 128 + tid;
    const float* wp1 = wp0 + 64;
    for (int k0 = 0; k0 < 256; k0 += KC) {
        for (int i = tid; i < ROWS * KC; i += 64) {
            int kk = i & 127, r = i >> 7;
            xs[kk * PAD + r] = QB[(size_t)(n0 + r) * QLD + 128 + kb + k0 + kk];
        }
        __syncthreads();
#pragma unroll 4
        for (int kk = 0; kk < KC; ++kk) {
            const float* xr = xs + kk * PAD;
            float xv[ROWS];
            float4* xvv = (float4*)xv;
            xvv[0] = *(const float4*)(xr);
            xvv[1] = *(const float4*)(xr + 4);
            xvv[2] = *(const float4*)(xr + 8);
            xvv[3] = *(const float4*)(xr + 12);
            float w0 = *wp0; wp0 += 128;
            float w1 = *wp1; wp1 += 128;
#pragma unroll
            for (int r = 0; r < ROWS; ++r) {
                acc0[r] = fmaf(xv[r], w0, acc0[r]);
                acc1[r] = fmaf(xv[r], w1, acc1[r]);
            }
        }
        __syncthreads();
    }
    if (blockIdx.y == 0) {
        for (int i = tid; i < ROWS * 64; i += 64) {
            int r = i >> 6, j = i & 63;
            ts[j * PAD + r] = TB[(size_t)(n0 + r) * 64 + j];
        }
        __syncthreads();
#pragma unroll 4
        for (int j = 0; j < 64; ++j) {
            const float* tr = ts + j * PAD;
            float xv[ROWS];
            float4* xvv = (float4*)xv;
            xvv[0] = *(const float4*)(tr);
            xvv[1] = *(const float4*)(tr + 4);
            xvv[2] = *(const float4*)(tr + 8);
            xvv[3] = *(const float4*)(tr + 12);
            float w0 = Wet[j * 128 + tid];
            float w1 = Wet[j * 128 + tid + 64];
#pragma unroll
            for (int r = 0; r < ROWS; ++r) {
                acc0[r] = fmaf(xv[r], w0, acc0[r]);
                acc1[r] = fmaf(xv[r], w1, acc1[r]);
            }
        }
    }
#pragma unroll
    for (int r = 0; r < ROWS; ++r) {
        QB[(size_t)(n0 + r) * QLD + oo + tid]      = acc0[r];
        QB[(size_t)(n0 + r) * QLD + oo + tid + 64] = acc1[r];
    }
}

// ---------------- per-layer weight prep (warp per output) ----------------
__global__ void prep_k(const float* __restrict__ Ws, const float* __restrict__ bs,
                       const float* __restrict__ tW, const float* __restrict__ Wb,
                       const float* __restrict__ Wq, const float* __restrict__ bq,
                       const float* __restrict__ We, int Fin,
                       float* __restrict__ Wst, float* __restrict__ ws_z,
                       float* __restrict__ sbt, float* __restrict__ zb,
                       float* __restrict__ Wu, float* __restrict__ bu,
                       float* __restrict__ Wet, float* __restrict__ wez) {
    int w = (blockIdx.x * blockDim.x + threadIdx.x) >> 6;
    int lane = threadIdx.x & 63;
    int nW = Fin * 128;
    int o1 = nW, o2 = o1 + Fin, o3 = o2 + 128, o4 = o3 + 1;
    int o5 = o4 + Fin * 64, o6 = o5 + 64, o7 = o6 + 8192, total = o7 + 64;
    if (w >= total) return;
    float s = 0.f;
    if (w < o1) {
        int f = w >> 7, m = w & 127;
        for (int c = lane; c < 512; c += 64)
            s = fmaf(Ws[(size_t)f * 512 + c], tW[(size_t)c * 128 + m], s);
    } else if (w < o2) {
        int f = w - o1;
        for (int c = lane; c < 512; c += 64)
            s = fmaf(Ws[(size_t)f * 512 + c], Wb[512 + c] - Wb[1024 + c], s);
    } else if (w < o3) {
        int m = w - o2;
        for (int c = lane; c < 512; c += 64)
            s = fmaf(bs[c], tW[(size_t)c * 128 + m], s);
    } else if (w < o4) {
        for (int c = lane; c < 512; c += 64)
            s = fmaf(bs[c], Wb[512 + c] - Wb[1024 + c], s);
    } else if (w < o5) {   // Wu
        int q = w - o4; int f = q >> 6; int j2 = q & 63;
        int j = j2 & 15; int cb = (j2 >> 4) * 128;
        s = Wq[(size_t)f * 512 + cb + lane] * We[j * 512 + cb + lane]
          + Wq[(size_t)f * 512 + cb + lane + 64] * We[j * 512 + cb + lane + 64];
    } else if (w < o6) {   // bu
        int j2 = w - o5; int j = j2 & 15; int cb = (j2 >> 4) * 128;
        s = bq[cb + lane] * We[j * 512 + cb + lane]
          + bq[cb + lane + 64] * We[j * 512 + cb + lane + 64];
    } else if (w < o7) {   // Wet
        int q = w - o6; int j2 = q >> 7; int m = q & 127;
        int j = j2 & 15; int cb = (j2 >> 4) * 128;
        s = We[j * 512 + cb + lane] * tW[(size_t)(cb + lane) * 128 + m]
          + We[j * 512 + cb + lane + 64] * tW[(size_t)(cb + lane + 64) * 128 + m];
    } else {               // wez
        int j2 = w - o7; int j = j2 & 15; int cb = (j2 >> 4) * 128;
        s = We[j * 512 + cb + lane] * (Wb[cb + lane] + Wb[1024 + cb + lane])
          + We[j * 512 + cb + lane + 64] * (Wb[cb + lane + 64] + Wb[1024 + cb + lane + 64]);
    }
#pragma unroll
    for (int off = 32; off; off >>= 1) s += __shfl_xor(s, off, 64);
    if (lane == 0) {
        if (w < o1) Wst[w] = s;
        else if (w < o2) ws_z[w - o1] = s;
        else if (w < o3) sbt[w - o2] = s;
        else if (w < o4) zb[0] = s;
        else if (w < o5) Wu[w - o4] = s;
        else if (w < o6) bu[w - o5] = s;
        else if (w < o7) Wet[w - o6] = s;
        else wez[w - o7] = s;
    }
}

// ---------------- per-graph CSR build (edges of graph g are [g*512,(g+1)*512)) --------------
__global__ __launch_bounds__(128) void csr_graph_k(const int* __restrict__ src,
                                                   const int* __restrict__ dst,
                                                   int* __restrict__ row_start,
                                                   int* __restrict__ row_end,
                                                   int* __restrict__ colb,
                                                   int* __restrict__ eidb) {
    __shared__ int cnt[128], pref[128], cur[128];
    int g = blockIdx.x, t = threadIdx.x;
    cnt[t] = 0;
    __syncthreads();
    int e0 = g * 512, nb = g * 128;
    int dl[4], sl[4];
#pragma unroll
    for (int i = 0; i < 4; ++i) {
        int e = e0 + t + i * 128;
        dl[i] = dst[e] - nb;
        sl[i] = src[e];
        atomicAdd(&cnt[dl[i]], 1);
    }
    __syncthreads();
    pref[t] = cnt[t];
    __syncthreads();
    for (int st = 1; st < 128; st <<= 1) {
        int v = (t >= st) ? pref[t - st] : 0;
        __syncthreads();
        pref[t] += v;
        __syncthreads();
    }
    int ex = pref[t] - cnt[t];
    row_start[nb + t] = e0 + ex;
    row_end[nb + t]   = e0 + pref[t];
    cur[t] = ex;
    __syncthreads();
#pragma unroll
    for (int i = 0; i < 4; ++i) {
        int pos = atomicAdd(&cur[dl[i]], 1);
        colb[e0 + pos] = sl[i];
        eidb[e0 + pos] = e0 + t + i * 128;
    }
}

// ---------------- attention: U/T decomposition, no LDS, plain-exp softmax ----------------
__global__ __launch_bounds__(256) void attn_k(
        float* __restrict__ QB, const float* __restrict__ UB, float* __restrict__ TB,
        const int* __restrict__ row_start, const int* __restrict__ row_end,
        const int* __restrict__ colb, const int* __restrict__ eidb,
        const float* __restrict__ ea, const float* __restrict__ Wb,
        const float* __restrict__ wez, float* __restrict__ zOut4) {
    int tid = threadIdx.x;
    int head = tid >> 6, lane = tid & 63;
    int c0 = head * 128 + lane, c1 = c0 + 64;
    float w13a = Wb[c0] + Wb[1024 + c0];
    float w13b = Wb[c1] + Wb[1024 + c1];
    float wezv = (lane < 16) ? wez[head * 16 + lane] : 0.f;
    int nodeBase = blockIdx.x * 4;
    float o0v[4], o1v[4], tnv[4], zpv[4];
#pragma unroll
    for (int rr = 0; rr < 4; ++rr) {
        int node = nodeBase + rr;
        const float* Qr = QB + (size_t)node * QLD + 128;
        float q0 = Qr[c0], q1 = Qr[c1];
        float uu = (lane < 16) ? UB[(size_t)node * 64 + head * 16 + lane] : 0.f;
        float l = 0.f, a0 = 0.f, a1 = 0.f, t = 0.f;
        int beg = row_start[node], end = row_end[node];
        for (int j = beg; j < end; ++j) {
            int s = colb[j];
            int e = eidb[j];
            const float* Kr = QB + (size_t)s * QLD + 640;
            const float* Vr = QB + (size_t)s * QLD + 1152;
            float k0 = Kr[c0], k1 = Kr[c1];
            float v0 = Vr[c0], v1 = Vr[c1];
            float eav = (lane < 16) ? ea[(size_t)e * 16 + lane] : 0.f;
            float part = q0 * k0 + q1 * k1 + eav * uu;
#pragma unroll
            for (int off = 32; off; off >>= 1) part += __shfl_xor(part, off, 64);
            float w = expf(part * 0.08838834764831845f);  // 1/sqrt(128); alpha O(10), safe
            l += w;
            a0 = fmaf(w, v0, a0);
            a1 = fmaf(w, v1, a1);
            t  = fmaf(w, eav, t);
        }
        float inv = 1.f / (l + 1e-16f);
        o0v[rr] = a0 * inv;
        o1v[rr] = a1 * inv;
        tnv[rr] = t * inv;
        float zp = o0v[rr] * w13a + o1v[rr] * w13b + tnv[rr] * wezv;
#pragma unroll
        for (int off = 32; off; off >>= 1) zp += __shfl_xor(zp, off, 64);
        zpv[rr] = zp;
    }
#pragma unroll
    for (int rr = 0; rr < 4; ++rr) {
        int node = nodeBase + rr;
        float* Qr = QB + (size_t)node * QLD + 128;
        Qr[c0] = o0v[rr];
        Qr[c1] = o1v[rr];
        if (lane < 16) TB[(size_t)node * 64 + head * 16 + lane] = tnv[rr];
        if (lane == 0) zOut4[node * 4 + head] = zpv[rr];
    }
}

// ---------------- combine: x_next = relu(beta*(skipT+sbt) + (1-beta)*outT + tb) -------------
__global__ void combine_k(const float* __restrict__ x, int Fin,
                          const float* __restrict__ ws_z, const float* __restrict__ zb,
                          const float* __restrict__ zOut4, const float* __restrict__ B,
                          const float* __restrict__ sbt, const float* __restrict__ tb,
                          float* __restrict__ xn) {
    __shared__ float red[128];
    int node = blockIdx.x, t = threadIdx.x;  // 128
    red[t] = (t < Fin) ? x[(size_t)node * Fin + t] * ws_z[t] : 0.f;
    __syncthreads();
    for (int st = 64; st; st >>= 1) {
        if (t < st) red[t] += red[t + st];
        __syncthreads();
    }
    float z = zOut4[node * 4] + zOut4[node * 4 + 1] + zOut4[node * 4 + 2] + zOut4[node * 4 + 3]
            + red[0] + zb[0];
    float beta = 1.f / (1.f + expf(-z));
    const float* row = B + (size_t)node * QLD;
    float outT = row[640 + t] + row[1152 + t];
    float a = beta * (row[t] + sbt[t]) + (1.f - beta) * outT + tb[t];
    xn[(size_t)node * 128 + t] = fmaxf(a, 0.f);
}

// ---------------- batchnorm ----------------
__global__ void bn_stats_k(const float* __restrict__ x, int N, float* __restrict__ stats) {
    int c = threadIdx.x;  // 128
    float s = 0.f, ss = 0.f;
    for (int n = blockIdx.x; n < N; n += gridDim.x) {
        float v = x[(size_t)n * 128 + c];
        s += v; ss += v * v;
    }
    atomicAdd(&stats[c], s);
    atomicAdd(&stats[128 + c], ss);
}

__global__ void bn_apply_k(float* __restrict__ x, int N, const float* __restrict__ stats,
                           const float* __restrict__ g, const float* __restrict__ b) {
    int idx = blockIdx.x * blockDim.x + threadIdx.x;
    if (idx >= N * 128) return;
    int c = idx & 127;
    float m = stats[c] / (float)N;
    float var = fmaxf(stats[128 + c] / (float)N - m * m, 0.f);
    float inv = rsqrtf(var + 1e-5f);
    x[idx] = g[c] * (x[idx] - m) * inv + b[c];
}

// bn apply + pooling score in one pass (wave = node). grid N/4, block 256.
__global__ void bn_apply_score_k(float* __restrict__ x, int N, const float* __restrict__ stats,
                                 const float* __restrict__ g, const float* __restrict__ b,
                                 const float* __restrict__ w, float* __restrict__ s) {
    int node = blockIdx.x * 4 + (threadIdx.x >> 6);
    int lane = threadIdx.x & 63;
    int c0 = lane, c1 = lane + 64;
    float m0 = stats[c0] / (float)N;
    float v0 = fmaxf(stats[128 + c0] / (float)N - m0 * m0, 0.f);
    float m1 = stats[c1] / (float)N;
    float v1 = fmaxf(stats[128 + c1] / (float)N - m1 * m1, 0.f);
    float* row = x + (size_t)node * 128;
    float x0 = g[c0] * (row[c0] - m0) * rsqrtf(v0 + 1e-5f) + b[c0];
    float x1 = g[c1] * (row[c1] - m1) * rsqrtf(v1 + 1e-5f) + b[c1];
    row[c0] = x0;
    row[c1] = x1;
    float w0 = w[c0], w1 = w[c1];
    float p  = x0 * w0 + x1 * w1;
    float nw = w0 * w0 + w1 * w1;
#pragma unroll
    for (int off = 32; off; off >>= 1) {
        p  += __shfl_xor(p, off, 64);
        nw += __shfl_xor(nw, off, 64);
    }
    if (lane == 0) s[node] = p / sqrtf(nw);
}

// ---------------- pool0: topk + gather + readout + per-graph CSR rebuild --------------------
__global__ __launch_bounds__(128) void topk_pool0_k(
        const float* __restrict__ sc, const float* __restrict__ x,
        const int* __restrict__ src, const int* __restrict__ dst,
        float* __restrict__ xp, float* __restrict__ rep,
        int* __restrict__ row_start, int* __restrict__ row_end,
        int* __restrict__ colb, int* __restrict__ eidb) {
    __shared__ float ls[128], th[64];
    __shared__ int lk[128], rk[128], oon[64];
    __shared__ int cnt[64], pref[64], cur[64];
    int g = blockIdx.x, t = threadIdx.x;
    float val = sc[g * 128 + t];
    ls[t] = val;
    __syncthreads();
    int c = 0;
    for (int j = 0; j < 128; ++j) {
        float vj = ls[j];
        c += (vj > val || (vj == val && j < t)) ? 1 : 0;
    }
    int kp = (c < 64) ? 1 : 0;
    lk[t] = kp;
    __syncthreads();
    int r = 0;
    for (int j = 0; j < t; ++j) r += lk[j];
    rk[t] = r;
    if (kp) { oon[r] = t; th[r] = tanhf(val); }
    __syncthreads();
    float mx = -INFINITY, sm = 0.f;
    for (int rr = 0; rr < 64; ++rr) {
        float v = x[(size_t)(g * 128 + oon[rr]) * 128 + t] * th[rr];
        xp[(size_t)(g * 64 + rr) * 128 + t] = v;
        mx = fmaxf(mx, v);
        sm += v;
    }
    rep[g * 256 + t] = mx;
    rep[g * 256 + 128 + t] = sm * (1.f / 64.f);
    if (t < 64) cnt[t] = 0;
    __syncthreads();
    int e0 = g * 512, nb = g * 128;
    int keepE[4], dr[4], sr[4];
#pragma unroll
    for (int i = 0; i < 4; ++i) {
        int e = e0 + t + i * 128;
        int s_ = src[e] - nb, d_ = dst[e] - nb;
        int ke = lk[s_] && lk[d_];
        keepE[i] = ke;
        dr[i] = rk[d_];
        sr[i] = rk[s_];
        if (ke) atomicAdd(&cnt[dr[i]], 1);
    }
    __syncthreads();
    if (t < 64) pref[t] = cnt[t];
    __syncthreads();
    for (int st = 1; st < 64; st <<= 1) {
        int v = (t < 64 && t >= st) ? pref[t - st] : 0;
        __syncthreads();
        if (t < 64) pref[t] += v;
        __syncthreads();
    }
    if (t < 64) {
        int ex = pref[t] - cnt[t];
        row_start[g * 64 + t] = e0 + ex;
        row_end[g * 64 + t]   = e0 + pref[t];
        cur[t] = ex;
    }
    __syncthreads();
#pragma unroll
    for (int i = 0; i < 4; ++i) {
        if (keepE[i]) {
            int pos = atomicAdd(&cur[dr[i]], 1);
            colb[e0 + pos] = g * 64 + sr[i];
            eidb[e0 + pos] = e0 + t + i * 128;
        }
    }
}

// ---------------- pool1: topk + readout only. n=64 -> k=32. block 128. ----------------------
__global__ __launch_bounds__(128) void topk_pool1_k(
        const float* __restrict__ sc, const float* __restrict__ x,
        float* __restrict__ rep) {
    __shared__ float ls[64], th[32];
    __shared__ int lk[64], oon[32];
    int g = blockIdx.x, t = threadIdx.x;
    float val = 0.f;
    if (t < 64) { val = sc[g * 64 + t]; ls[t] = val; }
    __syncthreads();
    if (t < 64) {
        int c = 0;
        for (int j = 0; j < 64; ++j) {
            float vj = ls[j];
            c += (vj > val || (vj == val && j < t)) ? 1 : 0;
        }
        int kp = (c < 32) ? 1 : 0;
        lk[t] = kp;
    }
    __syncthreads();
    if (t < 64 && lk[t]) {
        int r = 0;
        for (int j = 0; j < t; ++j) r += lk[j];
        oon[r] = t;
        th[r] = tanhf(val);
    }
    __syncthreads();
    float mx = -INFINITY, sm = 0.f;
    for (int rr = 0; rr < 32; ++rr) {
        float v = x[(size_t)(g * 64 + oon[rr]) * 128 + t] * th[rr];
        mx = fmaxf(mx, v);
        sm += v;
    }
    rep[g * 256 + t] = mx;
    rep[g * 256 + 128 + t] = sm * (1.f / 32.f);
}

// ---------------- MLP head: one block per graph, fp32 output ----------------
__global__ void head_k(const float* __restrict__ rep0, const float* __restrict__ rep1,
                       const float* __restrict__ W1, const float* __restrict__ b1,
                       const float* __restrict__ W2, const float* __restrict__ b2,
                       const float* __restrict__ W3, const float* __restrict__ b3,
                       float* __restrict__ out) {
    __shared__ float h[256], a1[256], a2[128], red[256];
    int g = blockIdx.x, t = threadIdx.x;  // 256
    h[t] = rep0[g * 256 + t] + rep1[g * 256 + t];
    __syncthreads();
    float acc = b1[t];
    for (int i = 0; i < 256; ++i) acc = fmaf(h[i], W1[i * 256 + t], acc);
    a1[t] = fmaxf(acc, 0.f);
    __syncthreads();
    if (t < 128) {
        float a = b2[t];
        for (int i = 0; i < 256; ++i) a = fmaf(a1[i], W2[i * 128 + t], a);
        a2[t] = fmaxf(a, 0.f);
    }
    __syncthreads();
    red[t] = (t < 128) ? a2[t] * W3[t] : 0.f;
    __syncthreads();
    for (int st = 128; st; st >>= 1) {
        if (t < st) red[t] += red[t + st];
        __syncthreads();
    }
    if (t == 0) out[g] = red[0] + b3[0];
}

// ======================================================================================
extern "C" void kernel_launch(void* const* d_in, const int* in_sizes, int n_in,
                              void* d_out, int out_size, void* d_ws, size_t ws_size,
                              hipStream_t stream) {
    (void)in_sizes; (void)n_in; (void)out_size; (void)ws_size;

    const float* x0    = (const float*)d_in[0];
    const int*   ei    = (const int*)d_in[1];
    const float* ea    = (const float*)d_in[2];
    const float* c1_Wq = (const float*)d_in[3];
    const float* c1_bq = (const float*)d_in[4];
    const float* c1_Wk = (const float*)d_in[5];
    const float* c1_bk = (const float*)d_in[6];
    const float* c1_Wv = (const float*)d_in[7];
    const float* c1_bv = (const float*)d_in[8];
    const float* c1_We = (const float*)d_in[9];
    const float* c1_Ws = (const float*)d_in[10];
    const float* c1_bs = (const float*)d_in[11];
    const float* c1_Wb = (const float*)d_in[12];
    const float* t1_W  = (const float*)d_in[13];
    const float* t1_b  = (const float*)d_in[14];
    const float* bn1_g = (const float*)d_in[15];
    const float* bn1_b = (const float*)d_in[16];
    const float* cl_Wq = (const float*)d_in[17];
    const float* cl_bq = (const float*)d_in[18];
    const float* cl_Wk = (const float*)d_in[19];
    const float* cl_bk = (const float*)d_in[20];
    const float* cl_Wv = (const float*)d_in[21];
    const float* cl_bv = (const float*)d_in[22];
    const float* cl_We = (const float*)d_in[23];
    const float* cl_Ws = (const float*)d_in[24];
    const float* cl_bs = (const float*)d_in[25];
    const float* cl_Wb = (const float*)d_in[26];
    const float* tl_W  = (const float*)d_in[27];
    const float* tl_b  = (const float*)d_in[28];
    const float* bnl_g = (const float*)d_in[29];
    const float* bnl_b = (const float*)d_in[30];
    const float* pool_w= (const float*)d_in[31];
    const float* l1_W  = (const float*)d_in[32];
    const float* l1_b  = (const float*)d_in[33];
    const float* l2_W  = (const float*)d_in[34];
    const float* l2_b  = (const float*)d_in[35];
    const float* l3_W  = (const float*)d_in[36];
    const float* l3_b  = (const float*)d_in[37];
    float* out = (float*)d_out;

    // -------- workspace layout (~128 MB) --------
    char* base = (char*)d_ws;
    size_t off = 0;
    auto alloc = [&](size_t bytes) -> void* {
        void* p = base + off;
        off += (bytes + 255) & ~(size_t)255;
        return p;
    };
    float* QB   = (float*)alloc((size_t)16384 * QLD * 4);   // 109 MB
    float* xA   = (float*)alloc((size_t)16384 * 128 * 4);
    float* xB   = (float*)alloc((size_t)16384 * 128 * 4);
    float* zOut4= (float*)alloc((size_t)16384 * 4 * 4);
    float* Wst  = (float*)alloc(128 * 128 * 4);
    float* ws_z = (float*)alloc(128 * 4);
    float* sbt  = (float*)alloc(128 * 4);
    float* zb   = (float*)alloc(4 * 4);
    float* Wu   = (float*)alloc(128 * 64 * 4);
    float* bu   = (float*)alloc(64 * 4);
    float* Wet  = (float*)alloc(64 * 128 * 4);
    float* wez  = (float*)alloc(64 * 4);
    float* stats  = (float*)alloc(256 * 4);
    float* scores = (float*)alloc(16384 * 4);
    float* rep0   = (float*)alloc(128 * 256 * 4);
    float* rep1   = (float*)alloc(128 * 256 * 4);
    int* row_start = (int*)alloc(16384 * 4);
    int* row_end   = (int*)alloc(16384 * 4);
    int* colb      = (int*)alloc(E_TOT * 4);
    int* eidb      = (int*)alloc(E_TOT * 4);
    unsigned short* Whi = (unsigned short*)alloc((size_t)NCOL * 128 * 2);
    unsigned short* Wlo = (unsigned short*)alloc((size_t)NCOL * 128 * 2);
    float* xp = xA;           // alias: xA dead once loop-0's combine has consumed it
    float* UB = xB;           // alias: U lives in xB's first half during a tconv
    float* TB = xB + (size_t)16384 * 64;  // alias: T in xB's second half (dead before combine)

    // Full tconv + t-layer(+bias+relu): xn = relu(gated @ tW + tb)
    auto tconv = [&](const float* xin, int N, int Fin,
                     const float* Wq, const float* bq, const float* Wk, const float* bk,
                     const float* Wv, const float* bv, const float* We,
                     const float* Ws, const float* bs, const float* Wb,
                     const float* tW, const float* tb, float* xn) {
        int total = Fin * 128 + Fin + 129 + Fin * 64 + 64 + 8192 + 64;
        prep_k<<<(total + 3) / 4, 256, 0, stream>>>(Ws, bs, tW, Wb, Wq, bq, We, Fin,
                                                    Wst, ws_z, sbt, zb, Wu, bu, Wet, wez);
        int kshift = (Fin == 64) ? 6 : 7;
        wsplit_k<<<(NCOL * Fin + 255) / 256, 256, 0, stream>>>(Wst, Wq, Wk, Wv, Wu,
                                                               Fin, kshift, Whi, Wlo);
        if (Fin == 64)
            qkvs_mfma<64><<<dim3(27, N / 64), 256, 0, stream>>>(xin, Whi, Wlo,
                                                                bq, bk, bv, bu, QB, UB);
        else
            qkvs_mfma<128><<<dim3(27, N / 64), 256, 0, stream>>>(xin, Whi, Wlo,
                                                                 bq, bk, bv, bu, QB, UB);
        attn_k<<<N / 4, 256, 0, stream>>>(QB, UB, TB, row_start, row_end, colb, eidb,
                                          ea, Wb, wez, zOut4);
        out_gemm<<<dim3(N / 16, 2), 64, 0, stream>>>(QB, tW, TB, Wet);
        combine_k<<<N, 128, 0, stream>>>(xin, Fin, ws_z, zb, zOut4, QB, sbt, tb, xn);
    };

    // ---- CSR over original edges (per-graph, one kernel) ----
    csr_graph_k<<<B_G, 128, 0, stream>>>(ei, ei + E_TOT, row_start, row_end, colb, eidb);

    // ---- layer 1: tconv(Fin=64) + t1 + bn1 ----
    tconv(x0, 16384, 64, c1_Wq, c1_bq, c1_Wk, c1_bk, c1_Wv, c1_bv, c1_We,
          c1_Ws, c1_bs, c1_Wb, t1_W, t1_b, xA);
    hipMemsetAsync(stats, 0, 256 * 4, stream);
    bn_stats_k<<<128, 128, 0, stream>>>(xA, 16384, stats);
    bn_apply_k<<<(16384 * 128 + 255) / 256, 256, 0, stream>>>(xA, 16384, stats, bn1_g, bn1_b);

    // ---- loop layer 0 (Fin=128, N=16384) ----
    tconv(xA, 16384, 128, cl_Wq, cl_bq, cl_Wk, cl_bk, cl_Wv, cl_bv, cl_We,
          cl_Ws, cl_bs, cl_Wb, tl_W, tl_b, xB);
    hipMemsetAsync(stats, 0, 256 * 4, stream);
    bn_stats_k<<<128, 128, 0, stream>>>(xB, 16384, stats);
    bn_apply_score_k<<<16384 / 4, 256, 0, stream>>>(xB, 16384, stats, bnl_g, bnl_b,
                                                    pool_w, scores);

    // ---- pool 0 (fused topk+gather+readout+CSR) ----
    topk_pool0_k<<<B_G, 128, 0, stream>>>(scores, xB, ei, ei + E_TOT, xp, rep0,
                                          row_start, row_end, colb, eidb);

    // ---- loop layer 1 (Fin=128, N=8192) ----
    tconv(xp, 8192, 128,
          cl_Wq + 65536, cl_bq + 512, cl_Wk + 65536, cl_bk + 512,
          cl_Wv + 65536, cl_bv + 512, cl_We + 8192,
          cl_Ws + 65536, cl_bs + 512, cl_Wb + 1536,
          tl_W + 65536, tl_b + 128, xB);
    hipMemsetAsync(stats, 0, 256 * 4, stream);
    bn_stats_k<<<128, 128, 0, stream>>>(xB, 8192, stats);
    bn_apply_score_k<<<8192 / 4, 256, 0, stream>>>(xB, 8192, stats, bnl_g + 128, bnl_b + 128,
                                                   pool_w + 128, scores);

    // ---- pool 1 (fused topk+readout) ----
    topk_pool1_k<<<B_G, 128, 0, stream>>>(scores, xB, rep1);

    // ---- MLP head (fp32 out) ----
    head_k<<<B_G, 256, 0, stream>>>(rep0, rep1, l1_W, l1_b, l2_W, l2_b, l3_W, l3_b, out);
}

// Round 15
// 694.888 us; speedup vs baseline: 1.7559x; 1.0610x over previous
//
#include <hip/hip_runtime.h>
#include <math.h>

#define E_TOT 65536
#define B_G   128
#define QLD   1664   // fused buffer row: [S(128) | Q(512, cols 128-255 reused for outT) | K(512) | VT(512)]
#define NCOL  1792   // GEMM cols: S|Q|K|VT (1664) + U(64) + VZ(4) + pad(60, masked)

typedef __attribute__((ext_vector_type(8))) short short8;
typedef __attribute__((ext_vector_type(4))) float float4v;

__device__ __forceinline__ unsigned short f2bf(float f) {
    unsigned int u = __float_as_uint(f);
    unsigned int r = u + 0x7FFFu + ((u >> 16) & 1u);   // round-to-nearest-even
    return (unsigned short)(r >> 16);
}
__device__ __forceinline__ float bf2f(unsigned short h) {
    return __uint_as_float(((unsigned int)h) << 16);
}

// Wt[col][k] transposed+split from [Wst | Wq | Wk | Wvt | Wu | Wvz | pad]
__global__ void wsplit_k(const float* __restrict__ Wst, const float* __restrict__ Wq,
                         const float* __restrict__ Wk, const float* __restrict__ Wvt,
                         const float* __restrict__ Wu, const float* __restrict__ Wvz,
                         int K, int kshift, unsigned short* __restrict__ Whi,
                         unsigned short* __restrict__ Wlo) {
    int idx = blockIdx.x * 256 + threadIdx.x;
    if (idx >= NCOL * K) return;
    int col = idx >> kshift, k = idx & (K - 1);
    float w;
    if (col < 128)       w = Wst[k * 128 + col];
    else if (col < 640)  w = Wq[(size_t)k * 512 + col - 128];
    else if (col < 1152) w = Wk[(size_t)k * 512 + col - 640];
    else if (col < 1664) w = Wvt[(size_t)k * 512 + col - 1152];
    else if (col < 1728) w = Wu[(size_t)k * 64 + col - 1664];
    else if (col < 1732) w = Wvz[(size_t)k * 4 + col - 1728];
    else                 w = 0.f;
    unsigned short h = f2bf(w);
    Whi[idx] = h;
    Wlo[idx] = f2bf(w - bf2f(h));
}

// ---------------- fused S/Q/K/VT/U/VZ GEMM via split-bf16 MFMA (fully static loops) ----------
// grid (28, N/64), block 256 (4 waves). Wave w: rows n0+w*16..+15, cols c0..c0+63.
template <int KT>
__global__ __launch_bounds__(256) void qkvs_mfma(
        const float* __restrict__ X,
        const unsigned short* __restrict__ Whi, const unsigned short* __restrict__ Wlo,
        const float* __restrict__ bq, const float* __restrict__ bk,
        const float* __restrict__ bvt, const float* __restrict__ bu,
        const float* __restrict__ bvz,
        float* __restrict__ out, float* __restrict__ UB, float* __restrict__ VZB) {
    constexpr int NKC = KT >> 5;            // 2 (K=64) or 4 (K=128)
    constexpr int NCH = KT >> 6;            // 1 or 2
    __shared__ __align__(16) unsigned short bs[2 * 64 * 80];   // 20 KB
    const int ldb = 80, loHalf = 64 * 80;
    int tid = threadIdx.x;
    int wave = tid >> 6, lane = tid & 63;
    int m = lane & 15, kg = lane >> 4;
    int n0 = blockIdx.y * 64 + wave * 16;
    int c0 = blockIdx.x * 64;

    const float* xr = X + (size_t)(n0 + m) * KT + kg * 8;
    short8 ahi[NKC], alo[NKC];
#pragma unroll
    for (int kc = 0; kc < NKC; ++kc) {
        float4 f0 = *(const float4*)(xr + kc * 32);
        float4 f1 = *(const float4*)(xr + kc * 32 + 4);
        float fv0 = f0.x, fv1 = f0.y, fv2 = f0.z, fv3 = f0.w;
        float fv4 = f1.x, fv5 = f1.y, fv6 = f1.z, fv7 = f1.w;
        unsigned short h0 = f2bf(fv0), h1 = f2bf(fv1), h2 = f2bf(fv2), h3 = f2bf(fv3);
        unsigned short h4 = f2bf(fv4), h5 = f2bf(fv5), h6 = f2bf(fv6), h7 = f2bf(fv7);
        short8 h = {(short)h0, (short)h1, (short)h2, (short)h3,
                    (short)h4, (short)h5, (short)h6, (short)h7};
        short8 l = {(short)f2bf(fv0 - bf2f(h0)), (short)f2bf(fv1 - bf2f(h1)),
                    (short)f2bf(fv2 - bf2f(h2)), (short)f2bf(fv3 - bf2f(h3)),
                    (short)f2bf(fv4 - bf2f(h4)), (short)f2bf(fv5 - bf2f(h5)),
                    (short)f2bf(fv6 - bf2f(h6)), (short)f2bf(fv7 - bf2f(h7))};
        ahi[kc] = h;
        alo[kc] = l;
    }

    float4v acc[4];
#pragma unroll
    for (int ct = 0; ct < 4; ++ct) acc[ct] = (float4v){0.f, 0.f, 0.f, 0.f};

#pragma unroll
    for (int ch = 0; ch < NCH; ++ch) {
        if (ch) __syncthreads();
        for (int i = tid; i < 64 * 8; i += 256) {
            int col = i >> 3, part = i & 7;
            *(short8*)(bs + col * ldb + part * 8) =
                *(const short8*)(Whi + (size_t)(c0 + col) * KT + ch * 64 + part * 8);
            *(short8*)(bs + loHalf + col * ldb + part * 8) =
                *(const short8*)(Wlo + (size_t)(c0 + col) * KT + ch * 64 + part * 8);
        }
        __syncthreads();
#pragma unroll
        for (int kc2 = 0; kc2 < 2; ++kc2) {
            const int kc = ch * 2 + kc2;    // compile-time constant after unroll
#pragma unroll
            for (int ct = 0; ct < 4; ++ct) {
                const unsigned short* bp = bs + (ct * 16 + m) * ldb + kg * 8 + kc2 * 32;
                short8 bhi = *(const short8*)(bp);
                short8 blo = *(const short8*)(bp + loHalf);
                acc[ct] = __builtin_amdgcn_mfma_f32_16x16x32_bf16(ahi[kc], bhi, acc[ct], 0, 0, 0);
                acc[ct] = __builtin_amdgcn_mfma_f32_16x16x32_bf16(alo[kc], bhi, acc[ct], 0, 0, 0);
                acc[ct] = __builtin_amdgcn_mfma_f32_16x16x32_bf16(ahi[kc], blo, acc[ct], 0, 0, 0);
            }
        }
    }

#pragma unroll
    for (int ct = 0; ct < 4; ++ct) {
        int col = c0 + ct * 16 + m;
        if (col >= 1732) continue;
        float bias;
        if (col < 128)       bias = 0.f;
        else if (col < 640)  bias = bq[col - 128];
        else if (col < 1152) bias = bk[col - 640];
        else if (col < 1664) bias = bvt[col - 1152];
        else if (col < 1728) bias = bu[col - 1664];
        else                 bias = bvz[col - 1728];
#pragma unroll
        for (int r = 0; r < 4; ++r) {
            int row = n0 + kg * 4 + r;
            float v = acc[ct][r] + bias;
            if (col < 1664)      out[(size_t)row * QLD + col] = v;
            else if (col < 1728) UB[(size_t)row * 64 + col - 1664] = v;
            else                 VZB[(size_t)row * 4 + col - 1728] = v;
        }
    }
}

// ---------------- per-layer weight prep (warp per output) ----------------
// Wst=Ws@tW; ws_z=Ws@(w2-w3); sbt=bs@tW; zb=bs@(w2-w3); Wu=Wq(.)We; bu; Wet=We@tW; wez=We.w13;
// Wvt[f,h128+m]=sum_c Wv[f,h128+c] tW[h128+c,m]; bvt likewise from bv;
// Wvz[f,h]=sum_c Wv[f,h128+c] w13[h128+c]; bvz from bv.
__global__ void prep_k(const float* __restrict__ Ws, const float* __restrict__ bs,
                       const float* __restrict__ tW, const float* __restrict__ Wb,
                       const float* __restrict__ Wq, const float* __restrict__ bq,
                       const float* __restrict__ We,
                       const float* __restrict__ Wv, const float* __restrict__ bv, int Fin,
                       float* __restrict__ Wst, float* __restrict__ ws_z,
                       float* __restrict__ sbt, float* __restrict__ zb,
                       float* __restrict__ Wu, float* __restrict__ bu,
                       float* __restrict__ Wet, float* __restrict__ wez,
                       float* __restrict__ Wvt, float* __restrict__ bvt,
                       float* __restrict__ Wvz, float* __restrict__ bvz) {
    int w = (blockIdx.x * blockDim.x + threadIdx.x) >> 6;
    int lane = threadIdx.x & 63;
    int o1 = Fin * 128, o2 = o1 + Fin, o3 = o2 + 128, o4 = o3 + 1;
    int o5 = o4 + Fin * 64, o6 = o5 + 64, o7 = o6 + 8192, o8 = o7 + 64;
    int o9 = o8 + Fin * 512, o10 = o9 + 512, o11 = o10 + Fin * 4, total = o11 + 4;
    if (w >= total) return;
    float s = 0.f;
    if (w < o1) {
        int f = w >> 7, m = w & 127;
        for (int c = lane; c < 512; c += 64)
            s = fmaf(Ws[(size_t)f * 512 + c], tW[(size_t)c * 128 + m], s);
    } else if (w < o2) {
        int f = w - o1;
        for (int c = lane; c < 512; c += 64)
            s = fmaf(Ws[(size_t)f * 512 + c], Wb[512 + c] - Wb[1024 + c], s);
    } else if (w < o3) {
        int m = w - o2;
        for (int c = lane; c < 512; c += 64)
            s = fmaf(bs[c], tW[(size_t)c * 128 + m], s);
    } else if (w < o4) {
        for (int c = lane; c < 512; c += 64)
            s = fmaf(bs[c], Wb[512 + c] - Wb[1024 + c], s);
    } else if (w < o5) {   // Wu
        int q = w - o4; int f = q >> 6; int j2 = q & 63;
        int j = j2 & 15; int cb = (j2 >> 4) * 128;
        s = Wq[(size_t)f * 512 + cb + lane] * We[j * 512 + cb + lane]
          + Wq[(size_t)f * 512 + cb + lane + 64] * We[j * 512 + cb + lane + 64];
    } else if (w < o6) {   // bu
        int j2 = w - o5; int j = j2 & 15; int cb = (j2 >> 4) * 128;
        s = bq[cb + lane] * We[j * 512 + cb + lane]
          + bq[cb + lane + 64] * We[j * 512 + cb + lane + 64];
    } else if (w < o7) {   // Wet
        int q = w - o6; int j2 = q >> 7; int m = q & 127;
        int j = j2 & 15; int cb = (j2 >> 4) * 128;
        s = We[j * 512 + cb + lane] * tW[(size_t)(cb + lane) * 128 + m]
          + We[j * 512 + cb + lane + 64] * tW[(size_t)(cb + lane + 64) * 128 + m];
    } else if (w < o8) {   // wez
        int j2 = w - o7; int j = j2 & 15; int cb = (j2 >> 4) * 128;
        s = We[j * 512 + cb + lane] * (Wb[cb + lane] + Wb[1024 + cb + lane])
          + We[j * 512 + cb + lane + 64] * (Wb[cb + lane + 64] + Wb[1024 + cb + lane + 64]);
    } else if (w < o9) {   // Wvt
        int q = w - o8; int f = q >> 9; int j2 = q & 511;
        int cb = (j2 >> 7) * 128; int m = j2 & 127;
        s = Wv[(size_t)f * 512 + cb + lane] * tW[(size_t)(cb + lane) * 128 + m]
          + Wv[(size_t)f * 512 + cb + lane + 64] * tW[(size_t)(cb + lane + 64) * 128 + m];
    } else if (w < o10) {  // bvt
        int j2 = w - o9; int cb = (j2 >> 7) * 128; int m = j2 & 127;
        s = bv[cb + lane] * tW[(size_t)(cb + lane) * 128 + m]
          + bv[cb + lane + 64] * tW[(size_t)(cb + lane + 64) * 128 + m];
    } else if (w < o11) {  // Wvz
        int q = w - o10; int f = q >> 2; int cb = (q & 3) * 128;
        s = Wv[(size_t)f * 512 + cb + lane] * (Wb[cb + lane] + Wb[1024 + cb + lane])
          + Wv[(size_t)f * 512 + cb + lane + 64] * (Wb[cb + lane + 64] + Wb[1024 + cb + lane + 64]);
    } else {               // bvz
        int cb = (w - o11) * 128;
        s = bv[cb + lane] * (Wb[cb + lane] + Wb[1024 + cb + lane])
          + bv[cb + lane + 64] * (Wb[cb + lane + 64] + Wb[1024 + cb + lane + 64]);
    }
#pragma unroll
    for (int off = 32; off; off >>= 1) s += __shfl_xor(s, off, 64);
    if (lane == 0) {
        if (w < o1) Wst[w] = s;
        else if (w < o2) ws_z[w - o1] = s;
        else if (w < o3) sbt[w - o2] = s;
        else if (w < o4) zb[0] = s;
        else if (w < o5) Wu[w - o4] = s;
        else if (w < o6) bu[w - o5] = s;
        else if (w < o7) Wet[w - o6] = s;
        else if (w < o8) wez[w - o7] = s;
        else if (w < o9) Wvt[w - o8] = s;
        else if (w < o10) bvt[w - o9] = s;
        else if (w < o11) Wvz[w - o10] = s;
        else bvz[w - o11] = s;
    }
}

// ---------------- per-graph CSR build (edges of graph g are [g*512,(g+1)*512)) --------------
__global__ __launch_bounds__(128) void csr_graph_k(const int* __restrict__ src,
                                                   const int* __restrict__ dst,
                                                   int* __restrict__ row_start,
                                                   int* __restrict__ row_end,
                                                   int* __restrict__ colb,
                                                   int* __restrict__ eidb) {
    __shared__ int cnt[128], pref[128], cur[128];
    int g = blockIdx.x, t = threadIdx.x;
    cnt[t] = 0;
    __syncthreads();
    int e0 = g * 512, nb = g * 128;
    int dl[4], sl[4];
#pragma unroll
    for (int i = 0; i < 4; ++i) {
        int e = e0 + t + i * 128;
        dl[i] = dst[e] - nb;
        sl[i] = src[e];
        atomicAdd(&cnt[dl[i]], 1);
    }
    __syncthreads();
    pref[t] = cnt[t];
    __syncthreads();
    for (int st = 1; st < 128; st <<= 1) {
        int v = (t >= st) ? pref[t - st] : 0;
        __syncthreads();
        pref[t] += v;
        __syncthreads();
    }
    int ex = pref[t] - cnt[t];
    row_start[nb + t] = e0 + ex;
    row_end[nb + t]   = e0 + pref[t];
    cur[t] = ex;
    __syncthreads();
#pragma unroll
    for (int i = 0; i < 4; ++i) {
        int pos = atomicAdd(&cur[dl[i]], 1);
        colb[e0 + pos] = sl[i];
        eidb[e0 + pos] = e0 + t + i * 128;
    }
}

// ---------------- attention: VT/VZ decomposition -> writes outT directly ----------------
// grid N/4, block 256 (wave = head). Per edge accumulates l, a(=sum w*VT), t(=sum w*ea),
// zac(=sum w*VZ). Epilogue: outT = cross-head sum of a/l -> QB cols 128..255 of node row.
__global__ __launch_bounds__(256) void attn_k(
        float* __restrict__ QB, const float* __restrict__ UB, const float* __restrict__ VZB,
        float* __restrict__ TB,
        const int* __restrict__ row_start, const int* __restrict__ row_end,
        const int* __restrict__ colb, const int* __restrict__ eidb,
        const float* __restrict__ ea, const float* __restrict__ wez,
        float* __restrict__ zOut4) {
    __shared__ float sh[4][128];
    int tid = threadIdx.x;
    int head = tid >> 6, lane = tid & 63;
    int c0 = head * 128 + lane, c1 = c0 + 64;
    float wezv = (lane < 16) ? wez[head * 16 + lane] : 0.f;
    int nodeBase = blockIdx.x * 4;
    for (int rr = 0; rr < 4; ++rr) {
        int node = nodeBase + rr;
        const float* Qr = QB + (size_t)node * QLD + 128;
        float q0 = Qr[c0], q1 = Qr[c1];
        float uu = (lane < 16) ? UB[(size_t)node * 64 + head * 16 + lane] : 0.f;
        float l = 0.f, a0 = 0.f, a1 = 0.f, t = 0.f, zac = 0.f;
        int beg = row_start[node], end = row_end[node];
        for (int j = beg; j < end; ++j) {
            int s = colb[j];
            int e = eidb[j];
            const float* Kr  = QB + (size_t)s * QLD + 640;
            const float* VTr = QB + (size_t)s * QLD + 1152;
            float k0 = Kr[c0], k1 = Kr[c1];
            float vt0 = VTr[c0], vt1 = VTr[c1];
            float vz = VZB[(size_t)s * 4 + head];
            float eav = (lane < 16) ? ea[(size_t)e * 16 + lane] : 0.f;
            float part = q0 * k0 + q1 * k1 + eav * uu;
#pragma unroll
            for (int off = 32; off; off >>= 1) part += __shfl_xor(part, off, 64);
            float w = expf(part * 0.08838834764831845f);  // 1/sqrt(128); alpha O(10), safe
            l += w;
            a0 = fmaf(w, vt0, a0);
            a1 = fmaf(w, vt1, a1);
            t  = fmaf(w, eav, t);
            zac = fmaf(w, vz, zac);
        }
        float inv = 1.f / (l + 1e-16f);
        float o0 = a0 * inv, o1 = a1 * inv;
        float tn = t * inv;
        float zw = tn * wezv;                       // nonzero only lanes<16
#pragma unroll
        for (int off = 8; off; off >>= 1) zw += __shfl_xor(zw, off, 64);  // sum within 16-group
        float z = zac * inv + zw;
        sh[head][lane] = o0;
        sh[head][lane + 64] = o1;
        if (lane < 16) TB[(size_t)node * 64 + head * 16 + lane] = tn;
        if (lane == 0) zOut4[node * 4 + head] = z;
        __syncthreads();
        if (tid < 128)
            QB[(size_t)node * QLD + 128 + tid] =
                sh[0][tid] + sh[1][tid] + sh[2][tid] + sh[3][tid];
        __syncthreads();
    }
}

// ---------------- combine: x_next = relu(beta*(skipT+sbt) + (1-beta)*(outT+tn@Wet) + tb) ----
__global__ void combine_k(const float* __restrict__ x, int Fin,
                          const float* __restrict__ ws_z, const float* __restrict__ zb,
                          const float* __restrict__ zOut4, const float* __restrict__ B,
                          const float* __restrict__ TB, const float* __restrict__ Wet,
                          const float* __restrict__ sbt, const float* __restrict__ tb,
                          float* __restrict__ xn) {
    __shared__ float red[128], tsh[64];
    int node = blockIdx.x, t = threadIdx.x;  // 128
    if (t < 64) tsh[t] = TB[(size_t)node * 64 + t];
    red[t] = (t < Fin) ? x[(size_t)node * Fin + t] * ws_z[t] : 0.f;
    __syncthreads();
    for (int st = 64; st; st >>= 1) {
        if (t < st) red[t] += red[t + st];
        __syncthreads();
    }
    float z = zOut4[node * 4] + zOut4[node * 4 + 1] + zOut4[node * 4 + 2] + zOut4[node * 4 + 3]
            + red[0] + zb[0];
    float beta = 1.f / (1.f + expf(-z));
    float wet = 0.f;
#pragma unroll 8
    for (int j = 0; j < 64; ++j) wet = fmaf(tsh[j], Wet[j * 128 + t], wet);
    const float* row = B + (size_t)node * QLD;
    float outT = row[128 + t] + wet;
    float a = beta * (row[t] + sbt[t]) + (1.f - beta) * outT + tb[t];
    xn[(size_t)node * 128 + t] = fmaxf(a, 0.f);
}

// ---------------- batchnorm ----------------
__global__ void bn_stats_k(const float* __restrict__ x, int N, float* __restrict__ stats) {
    int c = threadIdx.x;  // 128
    float s = 0.f, ss = 0.f;
    for (int n = blockIdx.x; n < N; n += gridDim.x) {
        float v = x[(size_t)n * 128 + c];
        s += v; ss += v * v;
    }
    atomicAdd(&stats[c], s);
    atomicAdd(&stats[128 + c], ss);
}

__global__ void bn_apply_k(float* __restrict__ x, int N, const float* __restrict__ stats,
                           const float* __restrict__ g, const float* __restrict__ b) {
    int idx = blockIdx.x * blockDim.x + threadIdx.x;
    if (idx >= N * 128) return;
    int c = idx & 127;
    float m = stats[c] / (float)N;
    float var = fmaxf(stats[128 + c] / (float)N - m * m, 0.f);
    float inv = rsqrtf(var + 1e-5f);
    x[idx] = g[c] * (x[idx] - m) * inv + b[c];
}

// bn apply + pooling score in one pass (wave = node). grid N/4, block 256.
__global__ void bn_apply_score_k(float* __restrict__ x, int N, const float* __restrict__ stats,
                                 const float* __restrict__ g, const float* __restrict__ b,
                                 const float* __restrict__ w, float* __restrict__ s) {
    int node = blockIdx.x * 4 + (threadIdx.x >> 6);
    int lane = threadIdx.x & 63;
    int c0 = lane, c1 = lane + 64;
    float m0 = stats[c0] / (float)N;
    float v0 = fmaxf(stats[128 + c0] / (float)N - m0 * m0, 0.f);
    float m1 = stats[c1] / (float)N;
    float v1 = fmaxf(stats[128 + c1] / (float)N - m1 * m1, 0.f);
    float* row = x + (size_t)node * 128;
    float x0 = g[c0] * (row[c0] - m0) * rsqrtf(v0 + 1e-5f) + b[c0];
    float x1 = g[c1] * (row[c1] - m1) * rsqrtf(v1 + 1e-5f) + b[c1];
    row[c0] = x0;
    row[c1] = x1;
    float w0 = w[c0], w1 = w[c1];
    float p  = x0 * w0 + x1 * w1;
    float nw = w0 * w0 + w1 * w1;
#pragma unroll
    for (int off = 32; off; off >>= 1) {
        p  += __shfl_xor(p, off, 64);
        nw += __shfl_xor(nw, off, 64);
    }
    if (lane == 0) s[node] = p / sqrtf(nw);
}

// ---------------- pool0: topk + gather + readout + per-graph CSR rebuild --------------------
__global__ __launch_bounds__(128) void topk_pool0_k(
        const float* __restrict__ sc, const float* __restrict__ x,
        const int* __restrict__ src, const int* __restrict__ dst,
        float* __restrict__ xp, float* __restrict__ rep,
        int* __restrict__ row_start, int* __restrict__ row_end,
        int* __restrict__ colb, int* __restrict__ eidb) {
    __shared__ float ls[128], th[64];
    __shared__ int lk[128], rk[128], oon[64];
    __shared__ int cnt[64], pref[64], cur[64];
    int g = blockIdx.x, t = threadIdx.x;
    float val = sc[g * 128 + t];
    ls[t] = val;
    __syncthreads();
    int c = 0;
    for (int j = 0; j < 128; ++j) {
        float vj = ls[j];
        c += (vj > val || (vj == val && j < t)) ? 1 : 0;
    }
    int kp = (c < 64) ? 1 : 0;
    lk[t] = kp;
    __syncthreads();
    int r = 0;
    for (int j = 0; j < t; ++j) r += lk[j];
    rk[t] = r;
    if (kp) { oon[r] = t; th[r] = tanhf(val); }
    __syncthreads();
    float mx = -INFINITY, sm = 0.f;
    for (int rr = 0; rr < 64; ++rr) {
        float v = x[(size_t)(g * 128 + oon[rr]) * 128 + t] * th[rr];
        xp[(size_t)(g * 64 + rr) * 128 + t] = v;
        mx = fmaxf(mx, v);
        sm += v;
    }
    rep[g * 256 + t] = mx;
    rep[g * 256 + 128 + t] = sm * (1.f / 64.f);
    if (t < 64) cnt[t] = 0;
    __syncthreads();
    int e0 = g * 512, nb = g * 128;
    int keepE[4], dr[4], sr[4];
#pragma unroll
    for (int i = 0; i < 4; ++i) {
        int e = e0 + t + i * 128;
        int s_ = src[e] - nb, d_ = dst[e] - nb;
        int ke = lk[s_] && lk[d_];
        keepE[i] = ke;
        dr[i] = rk[d_];
        sr[i] = rk[s_];
        if (ke) atomicAdd(&cnt[dr[i]], 1);
    }
    __syncthreads();
    if (t < 64) pref[t] = cnt[t];
    __syncthreads();
    for (int st = 1; st < 64; st <<= 1) {
        int v = (t < 64 && t >= st) ? pref[t - st] : 0;
        __syncthreads();
        if (t < 64) pref[t] += v;
        __syncthreads();
    }
    if (t < 64) {
        int ex = pref[t] - cnt[t];
        row_start[g * 64 + t] = e0 + ex;
        row_end[g * 64 + t]   = e0 + pref[t];
        cur[t] = ex;
    }
    __syncthreads();
#pragma unroll
    for (int i = 0; i < 4; ++i) {
        if (keepE[i]) {
            int pos = atomicAdd(&cur[dr[i]], 1);
            colb[e0 + pos] = g * 64 + sr[i];
            eidb[e0 + pos] = e0 + t + i * 128;
        }
    }
}

// ---------------- pool1: topk + readout only. n=64 -> k=32. block 128. ----------------------
__global__ __launch_bounds__(128) void topk_pool1_k(
        const float* __restrict__ sc, const float* __restrict__ x,
        float* __restrict__ rep) {
    __shared__ float ls[64], th[32];
    __shared__ int lk[64], oon[32];
    int g = blockIdx.x, t = threadIdx.x;
    float val = 0.f;
    if (t < 64) { val = sc[g * 64 + t]; ls[t] = val; }
    __syncthreads();
    if (t < 64) {
        int c = 0;
        for (int j = 0; j < 64; ++j) {
            float vj = ls[j];
            c += (vj > val || (vj == val && j < t)) ? 1 : 0;
        }
        int kp = (c < 32) ? 1 : 0;
        lk[t] = kp;
    }
    __syncthreads();
    if (t < 64 && lk[t]) {
        int r = 0;
        for (int j = 0; j < t; ++j) r += lk[j];
        oon[r] = t;
        th[r] = tanhf(val);
    }
    __syncthreads();
    float mx = -INFINITY, sm = 0.f;
    for (int rr = 0; rr < 32; ++rr) {
        float v = x[(size_t)(g * 64 + oon[rr]) * 128 + t] * th[rr];
        mx = fmaxf(mx, v);
        sm += v;
    }
    rep[g * 256 + t] = mx;
    rep[g * 256 + 128 + t] = sm * (1.f / 32.f);
}

// ---------------- MLP head: one block per graph, fp32 output ----------------
__global__ void head_k(const float* __restrict__ rep0, const float* __restrict__ rep1,
                       const float* __restrict__ W1, const float* __restrict__ b1,
                       const float* __restrict__ W2, const float* __restrict__ b2,
                       const float* __restrict__ W3, const float* __restrict__ b3,
                       float* __restrict__ out) {
    __shared__ float h[256], a1[256], a2[128], red[256];
    int g = blockIdx.x, t = threadIdx.x;  // 256
    h[t] = rep0[g * 256 + t] + rep1[g * 256 + t];
    __syncthreads();
    float acc = b1[t];
    for (int i = 0; i < 256; ++i) acc = fmaf(h[i], W1[i * 256 + t], acc);
    a1[t] = fmaxf(acc, 0.f);
    __syncthreads();
    if (t < 128) {
        float a = b2[t];
        for (int i = 0; i < 256; ++i) a = fmaf(a1[i], W2[i * 128 + t], a);
        a2[t] = fmaxf(a, 0.f);
    }
    __syncthreads();
    red[t] = (t < 128) ? a2[t] * W3[t] : 0.f;
    __syncthreads();
    for (int st = 128; st; st >>= 1) {
        if (t < st) red[t] += red[t + st];
        __syncthreads();
    }
    if (t == 0) out[g] = red[0] + b3[0];
}

// ======================================================================================
extern "C" void kernel_launch(void* const* d_in, const int* in_sizes, int n_in,
                              void* d_out, int out_size, void* d_ws, size_t ws_size,
                              hipStream_t stream) {
    (void)in_sizes; (void)n_in; (void)out_size; (void)ws_size;

    const float* x0    = (const float*)d_in[0];
    const int*   ei    = (const int*)d_in[1];
    const float* ea    = (const float*)d_in[2];
    const float* c1_Wq = (const float*)d_in[3];
    const float* c1_bq = (const float*)d_in[4];
    const float* c1_Wk = (const float*)d_in[5];
    const float* c1_bk = (const float*)d_in[6];
    const float* c1_Wv = (const float*)d_in[7];
    const float* c1_bv = (const float*)d_in[8];
    const float* c1_We = (const float*)d_in[9];
    const float* c1_Ws = (const float*)d_in[10];
    const float* c1_bs = (const float*)d_in[11];
    const float* c1_Wb = (const float*)d_in[12];
    const float* t1_W  = (const float*)d_in[13];
    const float* t1_b  = (const float*)d_in[14];
    const float* bn1_g = (const float*)d_in[15];
    const float* bn1_b = (const float*)d_in[16];
    const float* cl_Wq = (const float*)d_in[17];
    const float* cl_bq = (const float*)d_in[18];
    const float* cl_Wk = (const float*)d_in[19];
    const float* cl_bk = (const float*)d_in[20];
    const float* cl_Wv = (const float*)d_in[21];
    const float* cl_bv = (const float*)d_in[22];
    const float* cl_We = (const float*)d_in[23];
    const float* cl_Ws = (const float*)d_in[24];
    const float* cl_bs = (const float*)d_in[25];
    const float* cl_Wb = (const float*)d_in[26];
    const float* tl_W  = (const float*)d_in[27];
    const float* tl_b  = (const float*)d_in[28];
    const float* bnl_g = (const float*)d_in[29];
    const float* bnl_b = (const float*)d_in[30];
    const float* pool_w= (const float*)d_in[31];
    const float* l1_W  = (const float*)d_in[32];
    const float* l1_b  = (const float*)d_in[33];
    const float* l2_W  = (const float*)d_in[34];
    const float* l2_b  = (const float*)d_in[35];
    const float* l3_W  = (const float*)d_in[36];
    const float* l3_b  = (const float*)d_in[37];
    float* out = (float*)d_out;

    // -------- workspace layout (~133 MB) --------
    char* base = (char*)d_ws;
    size_t off = 0;
    auto alloc = [&](size_t bytes) -> void* {
        void* p = base + off;
        off += (bytes + 255) & ~(size_t)255;
        return p;
    };
    float* QB   = (float*)alloc((size_t)16384 * QLD * 4);   // 109 MB
    float* xA   = (float*)alloc((size_t)16384 * 128 * 4);
    float* xB   = (float*)alloc((size_t)16384 * 128 * 4);
    float* TB   = (float*)alloc((size_t)16384 * 64 * 4);    // 4.2 MB (own buffer: combine r/w hazard)
    float* VZB  = (float*)alloc((size_t)16384 * 4 * 4);
    float* zOut4= (float*)alloc((size_t)16384 * 4 * 4);
    float* Wst  = (float*)alloc(128 * 128 * 4);
    float* ws_z = (float*)alloc(128 * 4);
    float* sbt  = (float*)alloc(128 * 4);
    float* zb   = (float*)alloc(4 * 4);
    float* Wu   = (float*)alloc(128 * 64 * 4);
    float* bu   = (float*)alloc(64 * 4);
    float* Wet  = (float*)alloc(64 * 128 * 4);
    float* wez  = (float*)alloc(64 * 4);
    float* Wvt  = (float*)alloc(128 * 512 * 4);
    float* bvt  = (float*)alloc(512 * 4);
    float* Wvz  = (float*)alloc(128 * 4 * 4);
    float* bvz  = (float*)alloc(4 * 4);
    float* stats  = (float*)alloc(256 * 4);
    float* scores = (float*)alloc(16384 * 4);
    float* rep0   = (float*)alloc(128 * 256 * 4);
    float* rep1   = (float*)alloc(128 * 256 * 4);
    int* row_start = (int*)alloc(16384 * 4);
    int* row_end   = (int*)alloc(16384 * 4);
    int* colb      = (int*)alloc(E_TOT * 4);
    int* eidb      = (int*)alloc(E_TOT * 4);
    unsigned short* Whi = (unsigned short*)alloc((size_t)NCOL * 128 * 2);
    unsigned short* Wlo = (unsigned short*)alloc((size_t)NCOL * 128 * 2);
    float* xp = xA;           // alias: xA dead once loop-0's combine has consumed it
    float* UB = xB;           // alias: U lives in xB during a tconv (read only by attn)

    // Full tconv + t-layer(+bias+relu): xn = relu(gated @ tW + tb)
    auto tconv = [&](const float* xin, int N, int Fin,
                     const float* Wq, const float* bq, const float* Wk, const float* bk,
                     const float* Wv, const float* bv, const float* We,
                     const float* Ws, const float* bs, const float* Wb,
                     const float* tW, const float* tb, float* xn) {
        int total = Fin * 128 + Fin + 129 + Fin * 64 + 64 + 8192 + 64
                  + Fin * 512 + 512 + Fin * 4 + 4;
        prep_k<<<(total + 3) / 4, 256, 0, stream>>>(Ws, bs, tW, Wb, Wq, bq, We, Wv, bv, Fin,
                                                    Wst, ws_z, sbt, zb, Wu, bu, Wet, wez,
                                                    Wvt, bvt, Wvz, bvz);
        int kshift = (Fin == 64) ? 6 : 7;
        wsplit_k<<<(NCOL * Fin + 255) / 256, 256, 0, stream>>>(Wst, Wq, Wk, Wvt, Wu, Wvz,
                                                               Fin, kshift, Whi, Wlo);
        if (Fin == 64)
            qkvs_mfma<64><<<dim3(28, N / 64), 256, 0, stream>>>(xin, Whi, Wlo,
                                                                bq, bk, bvt, bu, bvz,
                                                                QB, UB, VZB);
        else
            qkvs_mfma<128><<<dim3(28, N / 64), 256, 0, stream>>>(xin, Whi, Wlo,
                                                                 bq, bk, bvt, bu, bvz,
                                                                 QB, UB, VZB);
        attn_k<<<N / 4, 256, 0, stream>>>(QB, UB, VZB, TB, row_start, row_end, colb, eidb,
                                          ea, wez, zOut4);
        combine_k<<<N, 128, 0, stream>>>(xin, Fin, ws_z, zb, zOut4, QB, TB, Wet,
                                         sbt, tb, xn);
    };

    // ---- CSR over original edges (per-graph, one kernel) ----
    csr_graph_k<<<B_G, 128, 0, stream>>>(ei, ei + E_TOT, row_start, row_end, colb, eidb);

    // ---- layer 1: tconv(Fin=64) + t1 + bn1 ----
    tconv(x0, 16384, 64, c1_Wq, c1_bq, c1_Wk, c1_bk, c1_Wv, c1_bv, c1_We,
          c1_Ws, c1_bs, c1_Wb, t1_W, t1_b, xA);
    hipMemsetAsync(stats, 0, 256 * 4, stream);
    bn_stats_k<<<128, 128, 0, stream>>>(xA, 16384, stats);
    bn_apply_k<<<(16384 * 128 + 255) / 256, 256, 0, stream>>>(xA, 16384, stats, bn1_g, bn1_b);

    // ---- loop layer 0 (Fin=128, N=16384) ----
    tconv(xA, 16384, 128, cl_Wq, cl_bq, cl_Wk, cl_bk, cl_Wv, cl_bv, cl_We,
          cl_Ws, cl_bs, cl_Wb, tl_W, tl_b, xB);
    hipMemsetAsync(stats, 0, 256 * 4, stream);
    bn_stats_k<<<128, 128, 0, stream>>>(xB, 16384, stats);
    bn_apply_score_k<<<16384 / 4, 256, 0, stream>>>(xB, 16384, stats, bnl_g, bnl_b,
                                                    pool_w, scores);

    // ---- pool 0 (fused topk+gather+readout+CSR) ----
    topk_pool0_k<<<B_G, 128, 0, stream>>>(scores, xB, ei, ei + E_TOT, xp, rep0,
                                          row_start, row_end, colb, eidb);

    // ---- loop layer 1 (Fin=128, N=8192) ----
    tconv(xp, 8192, 128,
          cl_Wq + 65536, cl_bq + 512, cl_Wk + 65536, cl_bk + 512,
          cl_Wv + 65536, cl_bv + 512, cl_We + 8192,
          cl_Ws + 65536, cl_bs + 512, cl_Wb + 1536,
          tl_W + 65536, tl_b + 128, xB);
    hipMemsetAsync(stats, 0, 256 * 4, stream);
    bn_stats_k<<<128, 128, 0, stream>>>(xB, 8192, stats);
    bn_apply_score_k<<<8192 / 4, 256, 0, stream>>>(xB, 8192, stats, bnl_g + 128, bnl_b + 128,
                                                   pool_w + 128, scores);

    // ---- pool 1 (fused topk+readout) ----
    topk_pool1_k<<<B_G, 128, 0, stream>>>(scores, xB, rep1);

    // ---- MLP head (fp32 out) ----
    head_k<<<B_G, 256, 0, stream>>>(rep0, rep1, l1_W, l1_b, l2_W, l2_b, l3_W, l3_b, out);
}